// Round 3
// baseline (653.754 us; speedup 1.0000x reference)
//
#include <hip/hip_runtime.h>
#include <hip/hip_bf16.h>
#include <stdint.h>

typedef __bf16 bf16;
typedef bf16 bf16x8 __attribute__((ext_vector_type(8)));
typedef bf16 bf16x4 __attribute__((ext_vector_type(4)));
typedef float f32x4 __attribute__((ext_vector_type(4)));
typedef int i32x4 __attribute__((ext_vector_type(4)));

#define N_TOK 8192
#define D_MODEL 1024
#define H_R 512
#define N_EXP 6
#define F_FF 1536
#define FLAG_CAP 1024

// Abramowitz-Stegun 7.1.26: |err| <= 1.5e-7
__device__ __forceinline__ float erf_fast(float x) {
    float ax = fabsf(x);
    float t = 1.0f / (1.0f + 0.3275911f * ax);
    float p = t * (0.254829592f + t * (-0.284496736f + t * (1.421413741f +
              t * (-1.453152027f + t * 1.061405429f))));
    float r = 1.0f - p * __expf(-ax * ax);
    return copysignf(r, x);
}
__device__ __forceinline__ float gelu_f(float x) {
    return 0.5f * x * (1.0f + erf_fast(x * 0.70710678118654752f));
}
__device__ __forceinline__ float silu_f(float x) {
    return x * (1.0f / (1.0f + __expf(-x)));
}

typedef __attribute__((address_space(1))) const void* gas1;
typedef __attribute__((address_space(3))) void* las3;

__device__ __forceinline__ void gload16(const void* g, void* l) {
    __builtin_amdgcn_global_load_lds((gas1)g, (las3)l, 16, 0, 0);
}

// LDS chunk swizzle for the 128x128 core (router): row r's logical 16B chunk q
// lives at chunk-slot (q + (r>>1)) & 3.
__device__ __forceinline__ int swz_src_q(int c) {
    return (((c & 3) - ((c >> 2) >> 1)) & 3);
}

// keep a value live without cost (anti-DCE, learn_hip rule #17)
#define SINK4(v) asm volatile("" :: "v"((v)[0]), "v"((v)[1]), "v"((v)[2]), "v"((v)[3]))

// ---------------- conversion / transpose ------------------------------------

__global__ __launch_bounds__(256) void convert_x_split(
    const float* __restrict__ x, bf16* __restrict__ xh, bf16* __restrict__ xl) {
    size_t i = ((size_t)blockIdx.x * 256 + threadIdx.x) * 8;
    f32x4 a = *(const f32x4*)(x + i);
    f32x4 b = *(const f32x4*)(x + i + 4);
    float v[8] = {a[0], a[1], a[2], a[3], b[0], b[1], b[2], b[3]};
    bf16x8 vh, vl;
    #pragma unroll
    for (int k = 0; k < 8; ++k) {
        bf16 h = (bf16)v[k];
        vh[k] = h;
        vl[k] = (bf16)(v[k] - (float)h);
    }
    *(bf16x8*)(xh + i) = vh;
    *(bf16x8*)(xl + i) = vl;
}

__global__ __launch_bounds__(256) void transpose_bf16_64(
    const float* __restrict__ in, bf16* __restrict__ out, int R, int C) {
    __shared__ float tile[64][65];
    const float* inp = in + (size_t)blockIdx.z * R * C;
    bf16* op = out + (size_t)blockIdx.z * R * C;
    int tx = threadIdx.x & 15, ty = threadIdx.x >> 4;
    int r0 = blockIdx.y * 64, c0 = blockIdx.x * 64;
    #pragma unroll
    for (int p = 0; p < 4; ++p) {
        int row = p * 16 + ty;
        f32x4 v = *(const f32x4*)(inp + (size_t)(r0 + row) * C + c0 + tx * 4);
        tile[row][tx * 4 + 0] = v[0];
        tile[row][tx * 4 + 1] = v[1];
        tile[row][tx * 4 + 2] = v[2];
        tile[row][tx * 4 + 3] = v[3];
    }
    __syncthreads();
    #pragma unroll
    for (int p = 0; p < 4; ++p) {
        int cc = p * 16 + ty;
        bf16x4 o;
        #pragma unroll
        for (int k = 0; k < 4; ++k) o[k] = (bf16)tile[tx * 4 + k][cc];
        *(bf16x4*)(op + (size_t)(c0 + cc) * R + r0 + tx * 4) = o;
    }
}

__global__ __launch_bounds__(256) void transpose_split(
    const float* __restrict__ in, bf16* __restrict__ oh, bf16* __restrict__ ol,
    int R, int C) {
    __shared__ float tile[32][33];
    int tx = threadIdx.x & 31, ty = threadIdx.x >> 5;
    int r0 = blockIdx.y * 32, c0 = blockIdx.x * 32;
    #pragma unroll
    for (int yy = ty; yy < 32; yy += 8)
        tile[yy][tx] = in[(size_t)(r0 + yy) * C + c0 + tx];
    __syncthreads();
    #pragma unroll
    for (int yy = ty; yy < 32; yy += 8) {
        float v = tile[tx][yy];
        bf16 h = (bf16)v;
        size_t o = (size_t)(c0 + yy) * R + r0 + tx;
        oh[o] = h;
        ol[o] = (bf16)(v - (float)h);
    }
}

// ---------------- 128x128 bf16 MFMA GEMM core (router path) -----------------

struct SMemStd {
    alignas(16) bf16 As[128 * 32];
    alignas(16) bf16 Bs[128 * 32];
};

__device__ __forceinline__ void gemm_core_async(
    const bf16* gA0, const bf16* gA1, const bf16* gB0, const bf16* gB1,
    int K, bf16* As, bf16* Bs, f32x4 acc[4][4]) {
    const int tid = threadIdx.x;
    const int lane = tid & 63;
    const int w = tid >> 6;
    const int wm = w & 1, wn = w >> 1;
    const int lc = lane & 15;
    const int koff = ((((lane >> 4) + (lc >> 1)) & 3) * 8);
    bf16* lA0 = As + w * 512;
    bf16* lA1 = As + 2048 + w * 512;
    bf16* lB0 = Bs + w * 512;
    bf16* lB1 = Bs + 2048 + w * 512;
    for (int kb = 0; kb < K; kb += 32) {
        __syncthreads();
        gload16(gA0 + kb, lA0);
        gload16(gA1 + kb, lA1);
        gload16(gB0 + kb, lB0);
        gload16(gB1 + kb, lB1);
        __syncthreads();
        bf16x8 af[4], bfr[4];
        #pragma unroll
        for (int i = 0; i < 4; ++i)
            af[i] = *(const bf16x8*)(As + (wm * 64 + i * 16 + lc) * 32 + koff);
        #pragma unroll
        for (int j = 0; j < 4; ++j)
            bfr[j] = *(const bf16x8*)(Bs + (wn * 64 + j * 16 + lc) * 32 + koff);
        #pragma unroll
        for (int i = 0; i < 4; ++i)
            #pragma unroll
            for (int j = 0; j < 4; ++j)
                acc[i][j] = __builtin_amdgcn_mfma_f32_16x16x32_bf16(af[i], bfr[j], acc[i][j], 0, 0, 0);
    }
}

// ---------------- 256x256 counted-vmcnt bf16 MFMA core (expert path) --------
// Template ablation (this round): STAGE / COMPUTE bits isolate the memory
// path (gload_lds+GATE+barriers) from the LDS+MFMA path (ds_read+MFMA+
// barriers). Real kernels use <true,true> — identical to round 2.

#define GATE(N) asm volatile("s_waitcnt vmcnt(" #N ")\n\ts_barrier" ::: "memory")

template<bool STAGE, bool COMPUTE>
__device__ __forceinline__ void gemm256_core(
    const bf16* a0, const bf16* a1, const bf16* a2, const bf16* a3,
    const bf16* b0, const bf16* b1, const bf16* b2, const bf16* b3,
    int K, bf16* As, bf16* Bs, f32x4 acc[8][4])
{
    const int tid = threadIdx.x;
    const int w = tid >> 6;
    const int lane = tid & 63;
    const int lc = lane & 15, qdv = lane >> 4;
    const int wm = w & 1, wn = w >> 1;
    const int wst = w * 512;              // wave staging offset (bf16 units)
    const int NT = K >> 6;
    // prologue: stage tile 0 into buf 0, issue order B0..B3, A0, A2, A1, A3
    if (STAGE) {
        gload16(b0, Bs + wst);
        gload16(b1, Bs + 4096 + wst);
        gload16(b2, Bs + 8192 + wst);
        gload16(b3, Bs + 12288 + wst);
        gload16(a0, As + wst);
        gload16(a2, As + 8192 + wst);
        gload16(a1, As + 4096 + wst);
        gload16(a3, As + 12288 + wst);
        a0 += 64; a1 += 64; a2 += 64; a3 += 64;
        b0 += 64; b1 += 64; b2 += 64; b3 += 64;
    }
    GATE(2);   // B0..B3, A0, A2 staged; A1, A3 still in flight
    const int rA0 = wm * 128 + lc;        // + i*16 (+64 for quadrant 1)
    const int rB0 = wn * 64 + lc;         // + j*16 (+32 for quadrant 1)
    int bo = 0;
    for (int t = 0; t < NT; ++t) {
        const int nb = bo ^ 16384;
        const bool pref = (t + 1 < NT);
        bf16x8 af[4][2], bfr[2][2];
        // ---- phase 0: read A(q0), B(q0); issue B0,B1(t+1); MFMA quad (0,0)
        if (COMPUTE) {
            #pragma unroll
            for (int i = 0; i < 4; ++i) {
                int row = rA0 + i * 16;
                #pragma unroll
                for (int s = 0; s < 2; ++s)
                    af[i][s] = *(const bf16x8*)(As + bo + row * 64 + (((s * 4 + qdv) + row) & 7) * 8);
            }
            #pragma unroll
            for (int j = 0; j < 2; ++j) {
                int row = rB0 + j * 16;
                #pragma unroll
                for (int s = 0; s < 2; ++s)
                    bfr[j][s] = *(const bf16x8*)(Bs + bo + row * 64 + (((s * 4 + qdv) + row) & 7) * 8);
            }
        }
        if (STAGE && pref) {
            gload16(b0, Bs + nb + wst);
            gload16(b1, Bs + nb + 4096 + wst);
        }
        __builtin_amdgcn_s_barrier();
        if (COMPUTE) {
            __builtin_amdgcn_s_setprio(1);
            #pragma unroll
            for (int i = 0; i < 4; ++i)
                #pragma unroll
                for (int j = 0; j < 2; ++j)
                    #pragma unroll
                    for (int s = 0; s < 2; ++s)
                        acc[i][j] = __builtin_amdgcn_mfma_f32_16x16x32_bf16(af[i][s], bfr[j][s], acc[i][j], 0, 0, 0);
            __builtin_amdgcn_s_setprio(0);
        }
        __builtin_amdgcn_s_barrier();
        // ---- phase 1: read B(q1); issue B2,B3(t+1); MFMA quad (0,1)
        if (COMPUTE) {
            #pragma unroll
            for (int j = 0; j < 2; ++j) {
                int row = rB0 + 32 + j * 16;
                #pragma unroll
                for (int s = 0; s < 2; ++s)
                    bfr[j][s] = *(const bf16x8*)(Bs + bo + row * 64 + (((s * 4 + qdv) + row) & 7) * 8);
            }
        }
        if (STAGE && pref) {
            gload16(b2, Bs + nb + 8192 + wst);
            gload16(b3, Bs + nb + 12288 + wst);
        }
        __builtin_amdgcn_s_barrier();
        if (COMPUTE) {
            __builtin_amdgcn_s_setprio(1);
            #pragma unroll
            for (int i = 0; i < 4; ++i)
                #pragma unroll
                for (int j = 0; j < 2; ++j)
                    #pragma unroll
                    for (int s = 0; s < 2; ++s)
                        acc[i][2 + j] = __builtin_amdgcn_mfma_f32_16x16x32_bf16(af[i][s], bfr[j][s], acc[i][2 + j], 0, 0, 0);
            __builtin_amdgcn_s_setprio(0);
        }
        if (pref) GATE(4);   // A1,A3 of tile t done; 4 newer (B01,B23) in flight
        else      GATE(0);   // last tile: nothing newer, must drain
        // ---- phase 2: read A(q1); issue A0,A2(t+1); MFMA quad (1,1)
        if (COMPUTE) {
            #pragma unroll
            for (int i = 0; i < 4; ++i) {
                int row = rA0 + 64 + i * 16;
                #pragma unroll
                for (int s = 0; s < 2; ++s)
                    af[i][s] = *(const bf16x8*)(As + bo + row * 64 + (((s * 4 + qdv) + row) & 7) * 8);
            }
        }
        if (STAGE && pref) {
            gload16(a0, As + nb + wst);
            gload16(a2, As + nb + 8192 + wst);
        }
        __builtin_amdgcn_s_barrier();
        if (COMPUTE) {
            __builtin_amdgcn_s_setprio(1);
            #pragma unroll
            for (int i = 0; i < 4; ++i)
                #pragma unroll
                for (int j = 0; j < 2; ++j)
                    #pragma unroll
                    for (int s = 0; s < 2; ++s)
                        acc[4 + i][2 + j] = __builtin_amdgcn_mfma_f32_16x16x32_bf16(af[i][s], bfr[j][s], acc[4 + i][2 + j], 0, 0, 0);
            __builtin_amdgcn_s_setprio(0);
        }
        __builtin_amdgcn_s_barrier();
        // ---- phase 3: re-read B(q0); issue A1,A3(t+1); MFMA quad (1,0)
        if (COMPUTE) {
            #pragma unroll
            for (int j = 0; j < 2; ++j) {
                int row = rB0 + j * 16;
                #pragma unroll
                for (int s = 0; s < 2; ++s)
                    bfr[j][s] = *(const bf16x8*)(Bs + bo + row * 64 + (((s * 4 + qdv) + row) & 7) * 8);
            }
        }
        if (STAGE && pref) {
            gload16(a1, As + nb + 4096 + wst);
            gload16(a3, As + nb + 12288 + wst);
            a0 += 64; a1 += 64; a2 += 64; a3 += 64;
            b0 += 64; b1 += 64; b2 += 64; b3 += 64;
        }
        __builtin_amdgcn_s_barrier();
        if (COMPUTE) {
            __builtin_amdgcn_s_setprio(1);
            #pragma unroll
            for (int i = 0; i < 4; ++i)
                #pragma unroll
                for (int j = 0; j < 2; ++j)
                    #pragma unroll
                    for (int s = 0; s < 2; ++s)
                        acc[4 + i][j] = __builtin_amdgcn_mfma_f32_16x16x32_bf16(af[i][s], bfr[j][s], acc[4 + i][j], 0, 0, 0);
            __builtin_amdgcn_s_setprio(0);
        }
        if (pref) GATE(2);   // next tile's B0..B3, A0, A2 staged; A1,A3 in flight
        else      __builtin_amdgcn_s_barrier();
        bo = nb;
    }
}

// ---------------- router GEMM1: z-split 3-term (fp32-accurate sum) ----------

__global__ __launch_bounds__(256) void router_gemm1_3(
    const bf16* __restrict__ xh, const bf16* __restrict__ xl,
    const bf16* __restrict__ wTh, const bf16* __restrict__ wTl,
    float* __restrict__ hp0, float* __restrict__ hp1, float* __restrict__ hp2) {
    __shared__ SMemStd sm;
    const int z = blockIdx.z;
    const bf16* Ab = (z == 2) ? xl : xh;
    const bf16* Bb = (z == 1) ? wTl : wTh;
    float* hp = (z == 0) ? hp0 : (z == 1 ? hp1 : hp2);
    const int tid = threadIdx.x;
    const int mbase = blockIdx.y * 128, nbase = blockIdx.x * 128;
    int c0 = tid, c1 = tid + 256;
    const bf16* gA0 = Ab + (size_t)(mbase + (c0 >> 2)) * D_MODEL + swz_src_q(c0) * 8;
    const bf16* gA1 = Ab + (size_t)(mbase + (c1 >> 2)) * D_MODEL + swz_src_q(c1) * 8;
    const bf16* Bt = Bb + (size_t)nbase * D_MODEL;
    const bf16* gB0 = Bt + (size_t)(c0 >> 2) * D_MODEL + swz_src_q(c0) * 8;
    const bf16* gB1 = Bt + (size_t)(c1 >> 2) * D_MODEL + swz_src_q(c1) * 8;
    f32x4 acc[4][4] = {};
    gemm_core_async(gA0, gA1, gB0, gB1, D_MODEL, sm.As, sm.Bs, acc);
    const int lane = tid & 63;
    const int w = tid >> 6;
    const int wm = w & 1, wn = w >> 1;
    const int lc = lane & 15, quad = lane >> 4;
    #pragma unroll
    for (int i = 0; i < 4; ++i)
        #pragma unroll
        for (int j = 0; j < 4; ++j) {
            int col = nbase + wn * 64 + j * 16 + lc;
            #pragma unroll
            for (int r = 0; r < 4; ++r) {
                int row = mbase + wm * 64 + i * 16 + quad * 4 + r;
                hp[(size_t)row * H_R + col] = acc[i][j][r];
            }
        }
}

// ---------------- fused LayerNorm + GELU + logits + top-2 -------------------

__global__ __launch_bounds__(256) void ln_router2(
    const float* __restrict__ hp0, const float* __restrict__ hp1,
    const float* __restrict__ hp2, const float* __restrict__ r1b,
    const float* __restrict__ g, const float* __restrict__ bta,
    const float* __restrict__ r2w, const float* __restrict__ r2b,
    const float* __restrict__ temp, const float* __restrict__ rbias,
    int* __restrict__ top_i, float* __restrict__ top_p,
    int* __restrict__ flaglist, int* __restrict__ meta) {
    __shared__ float Wl[H_R * N_EXP];
    int tid = threadIdx.x;
    for (int i = tid; i < H_R * N_EXP; i += 256) Wl[i] = r2w[i];
    __syncthreads();
    int w = tid >> 6, lane = tid & 63;
    int t = blockIdx.x * 4 + w;
    size_t rbase = (size_t)t * H_R;
    int k0 = lane * 8;
    float v[8];
    {
        f32x4 a0 = *(const f32x4*)(hp0 + rbase + k0);
        f32x4 a1 = *(const f32x4*)(hp0 + rbase + k0 + 4);
        f32x4 b0 = *(const f32x4*)(hp1 + rbase + k0);
        f32x4 b1 = *(const f32x4*)(hp1 + rbase + k0 + 4);
        f32x4 c0 = *(const f32x4*)(hp2 + rbase + k0);
        f32x4 c1 = *(const f32x4*)(hp2 + rbase + k0 + 4);
        f32x4 d0 = *(const f32x4*)(r1b + k0);
        f32x4 d1 = *(const f32x4*)(r1b + k0 + 4);
        #pragma unroll
        for (int k = 0; k < 4; ++k) {
            v[k]     = a0[k] + b0[k] + c0[k] + d0[k];
            v[k + 4] = a1[k] + b1[k] + c1[k] + d1[k];
        }
    }
    float s = 0.f;
    #pragma unroll
    for (int k = 0; k < 8; ++k) s += v[k];
    #pragma unroll
    for (int off = 32; off; off >>= 1) s += __shfl_xor(s, off);
    float mu = s * (1.0f / H_R);
    float q = 0.f;
    #pragma unroll
    for (int k = 0; k < 8; ++k) { float d = v[k] - mu; q += d * d; }
    #pragma unroll
    for (int off = 32; off; off >>= 1) q += __shfl_xor(q, off);
    float scl = 1.0f / sqrtf(q * (1.0f / H_R) + 1e-5f);
    f32x4 g0 = *(const f32x4*)(g + k0), g1 = *(const f32x4*)(g + k0 + 4);
    f32x4 b0 = *(const f32x4*)(bta + k0), b1v = *(const f32x4*)(bta + k0 + 4);
    float G[8] = {g0[0], g0[1], g0[2], g0[3], g1[0], g1[1], g1[2], g1[3]};
    float B[8] = {b0[0], b0[1], b0[2], b0[3], b1v[0], b1v[1], b1v[2], b1v[3]};
    float acc[N_EXP] = {};
    #pragma unroll
    for (int k = 0; k < 8; ++k) {
        float y = gelu_f((v[k] - mu) * scl * G[k] + B[k]);
        const float* wr = &Wl[(k0 + k) * N_EXP];
        #pragma unroll
        for (int e = 0; e < N_EXP; ++e) acc[e] += y * wr[e];
    }
    #pragma unroll
    for (int e = 0; e < N_EXP; ++e)
        #pragma unroll
        for (int off = 32; off; off >>= 1) acc[e] += __shfl_xor(acc[e], off);
    if (lane == 0) {
        float tinv = 1.0f / temp[0];
        float lg[N_EXP];
        #pragma unroll
        for (int e = 0; e < N_EXP; ++e) lg[e] = (acc[e] + r2b[e]) * tinv + rbias[e];
        float v1 = -1e30f; int i1 = 0;
        #pragma unroll
        for (int e = 0; e < N_EXP; ++e) if (lg[e] > v1) { v1 = lg[e]; i1 = e; }
        float v2 = -1e30f; int i2 = 0;
        #pragma unroll
        for (int e = 0; e < N_EXP; ++e) if (e != i1 && lg[e] > v2) { v2 = lg[e]; i2 = e; }
        float v3 = -1e30f;
        #pragma unroll
        for (int e = 0; e < N_EXP; ++e) if (e != i1 && e != i2 && lg[e] > v3) v3 = lg[e];
        float ssum = 0.f;
        #pragma unroll
        for (int e = 0; e < N_EXP; ++e) ssum += __expf(lg[e] - v1);
        float inv = 1.0f / ssum;
        top_i[2 * t] = i1; top_i[2 * t + 1] = i2;
        top_p[2 * t] = inv;
        top_p[2 * t + 1] = __expf(v2 - v1) * inv;
        if (v2 - v3 < 1e-3f) {
            int ix = atomicAdd(&meta[24], 1);
            if (ix < FLAG_CAP) flaglist[ix] = t;
        }
    }
}

// ---------------- fp64 exact rescue for near-tie tokens ---------------------

__global__ __launch_bounds__(256) void router_rescue(
    const float* __restrict__ x, const float* __restrict__ r1w,
    const float* __restrict__ r1b, const float* __restrict__ lng,
    const float* __restrict__ lnb, const float* __restrict__ r2w,
    const float* __restrict__ r2b, const float* __restrict__ temp,
    const float* __restrict__ rbias, const int* __restrict__ flaglist,
    const int* __restrict__ meta, int* __restrict__ top_i, float* __restrict__ top_p) {
    int n = meta[24]; if (n > FLAG_CAP) n = FLAG_CAP;
    if ((int)blockIdx.x >= n) return;
    int t = flaglist[blockIdx.x];
    __shared__ double xs[D_MODEL];
    __shared__ double hbuf[H_R];
    __shared__ double red[8];
    int tid = threadIdx.x;
    for (int k = tid; k < D_MODEL; k += 256) xs[k] = (double)x[(size_t)t * D_MODEL + k];
    __syncthreads();
    for (int c = tid; c < H_R; c += 256) {
        double s = 0.0;
        for (int k = 0; k < D_MODEL; ++k) s += xs[k] * (double)r1w[(size_t)k * H_R + c];
        hbuf[c] = s + (double)r1b[c];
    }
    __syncthreads();
    double ls = 0.0;
    for (int c = tid; c < H_R; c += 256) ls += hbuf[c];
    #pragma unroll
    for (int off = 32; off; off >>= 1) ls += __shfl_xor(ls, off);
    if ((tid & 63) == 0) red[tid >> 6] = ls;
    __syncthreads();
    double mu = (red[0] + red[1] + red[2] + red[3]) * (1.0 / H_R);
    __syncthreads();
    double q = 0.0;
    for (int c = tid; c < H_R; c += 256) { double d = hbuf[c] - mu; q += d * d; }
    #pragma unroll
    for (int off = 32; off; off >>= 1) q += __shfl_xor(q, off);
    if ((tid & 63) == 0) red[tid >> 6] = q;
    __syncthreads();
    double var = (red[0] + red[1] + red[2] + red[3]) * (1.0 / H_R);
    double scl = 1.0 / sqrt(var + 1e-5);
    __syncthreads();
    for (int c = tid; c < H_R; c += 256) {
        double y = (hbuf[c] - mu) * scl * (double)lng[c] + (double)lnb[c];
        hbuf[c] = 0.5 * y * (1.0 + erf(y * 0.70710678118654752440));
    }
    __syncthreads();
    if (tid < N_EXP) {
        double s = 0.0;
        for (int k = 0; k < H_R; ++k) s += hbuf[k] * (double)r2w[k * N_EXP + tid];
        red[tid] = (s + (double)r2b[tid]) / (double)temp[0] + (double)rbias[tid];
    }
    __syncthreads();
    if (tid == 0) {
        double lg[N_EXP];
        #pragma unroll
        for (int e = 0; e < N_EXP; ++e) lg[e] = red[e];
        double v1 = -1e300; int i1 = 0;
        for (int e = 0; e < N_EXP; ++e) if (lg[e] > v1) { v1 = lg[e]; i1 = e; }
        double v2 = -1e300; int i2 = 0;
        for (int e = 0; e < N_EXP; ++e) if (e != i1 && lg[e] > v2) { v2 = lg[e]; i2 = e; }
        double s = 0.0;
        for (int e = 0; e < N_EXP; ++e) s += exp(lg[e] - v1);
        double inv = 1.0 / s;
        top_i[2 * t] = i1; top_i[2 * t + 1] = i2;
        top_p[2 * t] = (float)inv;
        top_p[2 * t + 1] = (float)(exp(v2 - v1) * inv);
    }
}

// ---------------- route_pack: count + scan + scatter, zero global atomics ---

#define RP_T 1024
#define RP_TOK (N_TOK / RP_T)   // 8 tokens per thread

__global__ __launch_bounds__(1024) void route_pack(
    const int* __restrict__ top_i, int* __restrict__ meta,
    int* __restrict__ atok, int* __restrict__ ainv) {
    __shared__ int S[N_EXP][RP_T];
    __shared__ int segbase[N_EXP + 1];
    int tid = threadIdx.x;
    int e_loc[2 * RP_TOK];
    int cnt[N_EXP];
    #pragma unroll
    for (int e = 0; e < N_EXP; ++e) cnt[e] = 0;
    int t0 = tid * RP_TOK;
    #pragma unroll
    for (int q = 0; q < (2 * RP_TOK) / 4; ++q) {
        i32x4 v = *(const i32x4*)(top_i + 2 * t0 + q * 4);
        #pragma unroll
        for (int k = 0; k < 4; ++k) {
            int e = v[k];
            e_loc[q * 4 + k] = e;
            #pragma unroll
            for (int ee = 0; ee < N_EXP; ++ee) if (e == ee) cnt[ee]++;
        }
    }
    #pragma unroll
    for (int e = 0; e < N_EXP; ++e) S[e][tid] = cnt[e];
    __syncthreads();
    for (int off = 1; off < RP_T; off <<= 1) {
        int tmp[N_EXP];
        #pragma unroll
        for (int e = 0; e < N_EXP; ++e)
            tmp[e] = (tid >= off) ? S[e][tid - off] : 0;
        __syncthreads();
        #pragma unroll
        for (int e = 0; e < N_EXP; ++e) S[e][tid] += tmp[e];
        __syncthreads();
    }
    if (tid == 0) {
        int o = 0;
        #pragma unroll
        for (int e = 0; e < N_EXP; ++e) {
            segbase[e] = o;
            int tot = S[e][RP_T - 1];
            meta[e] = tot;
            meta[8 + e] = o;
            o += tot;
        }
        segbase[N_EXP] = o;
    }
    __syncthreads();
    int pos[N_EXP];
    #pragma unroll
    for (int e = 0; e < N_EXP; ++e)
        pos[e] = segbase[e] + S[e][tid] - cnt[e];
    #pragma unroll
    for (int k = 0; k < 2 * RP_TOK; ++k) {
        int e = e_loc[k];
        int a = 0;
        #pragma unroll
        for (int ee = 0; ee < N_EXP; ++ee) if (e == ee) a = pos[ee]++;
        atok[a] = t0 + (k >> 1);
        ainv[2 * t0 + k] = a;
    }
}

// ---------------- expert GEMMs: 256x256 counted-vmcnt pipeline --------------

__global__ __launch_bounds__(512, 2) void expert_gemm1(
    const bf16* __restrict__ xb, const bf16* __restrict__ W1T,
    const float* __restrict__ b1, const int* __restrict__ meta,
    const int* __restrict__ atok, bf16* __restrict__ act) {
    extern __shared__ bf16 smem[];         // [0,32768): A bufs, [32768,65536): B bufs
    int e = blockIdx.z;
    int rows = meta[e];
    int mloc = blockIdx.y * 256;
    if (mloc >= rows) return;
    int base = meta[8 + e];
    int tid = threadIdx.x;
    int nbase = blockIdx.x * 256;
    const int sr = tid >> 3;               // staging row within 64-row block
    const int sc = tid & 7;                // phys 16B chunk
    const bf16* ap[4];
    const bf16* bp[4];
    #pragma unroll
    for (int h = 0; h < 4; ++h) {
        int tr = h * 64 + sr;              // tile-local row 0..255
        int q = (sc - tr) & 7;             // logical chunk for this phys slot
        int rr = mloc + tr; if (rr > rows - 1) rr = rows - 1;
        ap[h] = xb + (size_t)atok[base + rr] * D_MODEL + q * 8;
        bp[h] = W1T + ((size_t)e * F_FF + nbase + tr) * D_MODEL + q * 8;
    }
    f32x4 acc[8][4] = {};
    gemm256_core<true, true>(ap[0], ap[1], ap[2], ap[3], bp[0], bp[1], bp[2], bp[3],
                             D_MODEL, smem, smem + 32768, acc);
    const int lane = tid & 63;
    const int w = tid >> 6;
    const int wm = w & 1, wn = w >> 1;
    const int lc = lane & 15, qd = lane >> 4;
    const bool oddE = (e & 1) != 0;
    #pragma unroll
    for (int ai = 0; ai < 8; ++ai) {
        int rt = wm * 128 + (ai >> 2) * 64 + (ai & 3) * 16 + qd * 4;
        #pragma unroll
        for (int aj = 0; aj < 4; ++aj) {
            int col = nbase + wn * 64 + (aj >> 1) * 32 + (aj & 1) * 16 + lc;
            float bias = b1[e * F_FF + col];
            #pragma unroll
            for (int r = 0; r < 4; ++r) {
                int rloc = mloc + rt + r;
                if (rloc < rows) {
                    float vv = acc[ai][aj][r] + bias;
                    vv = oddE ? silu_f(vv) : gelu_f(vv);
                    act[(size_t)(base + rloc) * F_FF + col] = (bf16)vv;
                }
            }
        }
    }
}

// ---- ablation probes: identical block-space/addressing, no output ----------

__global__ __launch_bounds__(512, 2) void eg1_probe_stage(
    const bf16* __restrict__ xb, const bf16* __restrict__ W1T,
    const int* __restrict__ meta, const int* __restrict__ atok) {
    extern __shared__ bf16 smem[];
    int e = blockIdx.z;
    int rows = meta[e];
    int mloc = blockIdx.y * 256;
    if (mloc >= rows) return;
    int base = meta[8 + e];
    int tid = threadIdx.x;
    int nbase = blockIdx.x * 256;
    const int sr = tid >> 3;
    const int sc = tid & 7;
    const bf16* ap[4];
    const bf16* bp[4];
    #pragma unroll
    for (int h = 0; h < 4; ++h) {
        int tr = h * 64 + sr;
        int q = (sc - tr) & 7;
        int rr = mloc + tr; if (rr > rows - 1) rr = rows - 1;
        ap[h] = xb + (size_t)atok[base + rr] * D_MODEL + q * 8;
        bp[h] = W1T + ((size_t)e * F_FF + nbase + tr) * D_MODEL + q * 8;
    }
    f32x4 acc[8][4] = {};
    gemm256_core<true, false>(ap[0], ap[1], ap[2], ap[3], bp[0], bp[1], bp[2], bp[3],
                              D_MODEL, smem, smem + 32768, acc);
}

__global__ __launch_bounds__(512, 2) void eg1_probe_mfma(
    const bf16* __restrict__ xb, const bf16* __restrict__ W1T,
    const int* __restrict__ meta, const int* __restrict__ atok) {
    extern __shared__ bf16 smem[];
    int e = blockIdx.z;
    int rows = meta[e];
    int mloc = blockIdx.y * 256;
    if (mloc >= rows) return;
    int base = meta[8 + e];
    int tid = threadIdx.x;
    int nbase = blockIdx.x * 256;
    const int sr = tid >> 3;
    const int sc = tid & 7;
    const bf16* ap[4];
    const bf16* bp[4];
    #pragma unroll
    for (int h = 0; h < 4; ++h) {
        int tr = h * 64 + sr;
        int q = (sc - tr) & 7;
        int rr = mloc + tr; if (rr > rows - 1) rr = rows - 1;
        ap[h] = xb + (size_t)atok[base + rr] * D_MODEL + q * 8;
        bp[h] = W1T + ((size_t)e * F_FF + nbase + tr) * D_MODEL + q * 8;
    }
    f32x4 acc[8][4] = {};
    gemm256_core<false, true>(ap[0], ap[1], ap[2], ap[3], bp[0], bp[1], bp[2], bp[3],
                              D_MODEL, smem, smem + 32768, acc);
    #pragma unroll
    for (int ai = 0; ai < 8; ++ai)
        #pragma unroll
        for (int aj = 0; aj < 4; ++aj)
            SINK4(acc[ai][aj]);
}

__global__ __launch_bounds__(512, 2) void expert_gemm2(
    const bf16* __restrict__ act, const bf16* __restrict__ W2T,
    const float* __restrict__ b2, const int* __restrict__ meta,
    float* __restrict__ eo) {
    extern __shared__ bf16 smem[];
    int e = blockIdx.z;
    int rows = meta[e];
    int mloc = blockIdx.y * 256;
    if (mloc >= rows) return;
    int base = meta[8 + e];
    int tid = threadIdx.x;
    int nbase = blockIdx.x * 256;
    const int sr = tid >> 3;
    const int sc = tid & 7;
    const bf16* ap[4];
    const bf16* bp[4];
    #pragma unroll
    for (int h = 0; h < 4; ++h) {
        int tr = h * 64 + sr;
        int q = (sc - tr) & 7;
        int rr = mloc + tr; if (rr > rows - 1) rr = rows - 1;
        ap[h] = act + (size_t)(base + rr) * F_FF + q * 8;
        bp[h] = W2T + ((size_t)e * D_MODEL + nbase + tr) * F_FF + q * 8;
    }
    f32x4 acc[8][4] = {};
    gemm256_core<true, true>(ap[0], ap[1], ap[2], ap[3], bp[0], bp[1], bp[2], bp[3],
                             F_FF, smem, smem + 32768, acc);
    const int lane = tid & 63;
    const int w = tid >> 6;
    const int wm = w & 1, wn = w >> 1;
    const int lc = lane & 15, qd = lane >> 4;
    #pragma unroll
    for (int ai = 0; ai < 8; ++ai) {
        int rt = wm * 128 + (ai >> 2) * 64 + (ai & 3) * 16 + qd * 4;
        #pragma unroll
        for (int aj = 0; aj < 4; ++aj) {
            int col = nbase + wn * 64 + (aj >> 1) * 32 + (aj & 1) * 16 + lc;
            float bias = b2[e * D_MODEL + col];
            #pragma unroll
            for (int r = 0; r < 4; ++r) {
                int rloc = mloc + rt + r;
                if (rloc < rows)
                    eo[(size_t)(base + rloc) * D_MODEL + col] = acc[ai][aj][r] + bias;
            }
        }
    }
}

// ---------------- weighted combine ------------------------------------------

__global__ __launch_bounds__(256) void combine_kernel(
    const float* __restrict__ eo, const int* __restrict__ ainv,
    const float* __restrict__ top_p, float* __restrict__ out) {
    int t = blockIdx.x;
    int s0 = ainv[2 * t], s1 = ainv[2 * t + 1];
    float p0 = top_p[2 * t], p1 = top_p[2 * t + 1];
    int c = threadIdx.x * 4;
    f32x4 a = *(const f32x4*)(eo + (size_t)s0 * D_MODEL + c);
    f32x4 b = *(const f32x4*)(eo + (size_t)s1 * D_MODEL + c);
    f32x4 o;
    #pragma unroll
    for (int k = 0; k < 4; ++k) o[k] = a[k] * p0 + b[k] * p1;
    *(f32x4*)(out + (size_t)t * D_MODEL + c) = o;
}

// ---------------- launch ----------------------------------------------------

extern "C" void kernel_launch(void* const* d_in, const int* in_sizes, int n_in,
                              void* d_out, int out_size, void* d_ws, size_t ws_size,
                              hipStream_t stream) {
    static bool attr_done = false;
    if (!attr_done) {
        hipFuncSetAttribute((const void*)expert_gemm1,
                            hipFuncAttributeMaxDynamicSharedMemorySize, 131072);
        hipFuncSetAttribute((const void*)expert_gemm2,
                            hipFuncAttributeMaxDynamicSharedMemorySize, 131072);
        hipFuncSetAttribute((const void*)eg1_probe_stage,
                            hipFuncAttributeMaxDynamicSharedMemorySize, 131072);
        hipFuncSetAttribute((const void*)eg1_probe_mfma,
                            hipFuncAttributeMaxDynamicSharedMemorySize, 131072);
        attr_done = true;
    }
    const float* x     = (const float*)d_in[0];
    const float* r1w   = (const float*)d_in[1];
    const float* r1b   = (const float*)d_in[2];
    const float* lng   = (const float*)d_in[3];
    const float* lnb   = (const float*)d_in[4];
    const float* r2w   = (const float*)d_in[5];
    const float* r2b   = (const float*)d_in[6];
    const float* temp  = (const float*)d_in[7];
    const float* rbias = (const float*)d_in[8];
    const float* W1    = (const float*)d_in[9];
    const float* b1    = (const float*)d_in[10];
    const float* W2    = (const float*)d_in[11];
    const float* b2    = (const float*)d_in[12];
    float* out = (float*)d_out;

    char* ws = (char*)d_ws;
    size_t off = 0;
    auto alloc = [&](size_t bytes) -> void* {
        void* p = ws + off;
        off = (off + bytes + 255) & ~(size_t)255;
        return p;
    };
    bf16*  xh    = (bf16*)alloc((size_t)N_TOK * D_MODEL * 2);
    bf16*  xl    = (bf16*)alloc((size_t)N_TOK * D_MODEL * 2);
    bf16*  r1wTh = (bf16*)alloc((size_t)H_R * D_MODEL * 2);
    bf16*  r1wTl = (bf16*)alloc((size_t)H_R * D_MODEL * 2);
    bf16*  W1T   = (bf16*)alloc((size_t)N_EXP * F_FF * D_MODEL * 2);
    bf16*  W2T   = (bf16*)alloc((size_t)N_EXP * D_MODEL * F_FF * 2);
    float* hp0   = (float*)alloc((size_t)N_TOK * H_R * 4);
    int*   top_i = (int*)alloc((size_t)N_TOK * 2 * 4);
    float* top_p = (float*)alloc((size_t)N_TOK * 2 * 4);
    int*   meta  = (int*)alloc(256);
    int*   flags = (int*)alloc(FLAG_CAP * 4);
    int*   atok  = (int*)alloc((size_t)2 * N_TOK * 4);
    int*   ainv  = (int*)alloc((size_t)2 * N_TOK * 4);
    bf16*  actb  = (bf16*)alloc((size_t)2 * N_TOK * F_FF * 2);
    float* eo    = (float*)alloc((size_t)2 * N_TOK * D_MODEL * 4);
    float* hp1 = (float*)actb;
    float* hp2 = (float*)((char*)actb + (size_t)N_TOK * H_R * 4);
    (void)ws_size; (void)n_in; (void)in_sizes;

    hipMemsetAsync(meta, 0, 256, stream);

    convert_x_split<<<(N_TOK * D_MODEL) / (256 * 8), 256, 0, stream>>>(x, xh, xl);
    transpose_split<<<dim3(H_R / 32, D_MODEL / 32, 1), 256, 0, stream>>>(
        r1w, r1wTh, r1wTl, D_MODEL, H_R);
    transpose_bf16_64<<<dim3(F_FF / 64, D_MODEL / 64, N_EXP), 256, 0, stream>>>(
        W1, W1T, D_MODEL, F_FF);
    transpose_bf16_64<<<dim3(D_MODEL / 64, F_FF / 64, N_EXP), 256, 0, stream>>>(
        W2, W2T, F_FF, D_MODEL);

    router_gemm1_3<<<dim3(H_R / 128, N_TOK / 128, 3), 256, 0, stream>>>(
        xh, xl, r1wTh, r1wTl, hp0, hp1, hp2);
    ln_router2<<<N_TOK / 4, 256, 0, stream>>>(
        hp0, hp1, hp2, r1b, lng, lnb, r2w, r2b, temp, rbias, top_i, top_p, flags, meta);
    router_rescue<<<FLAG_CAP, 256, 0, stream>>>(
        x, r1w, r1b, lng, lnb, r2w, r2b, temp, rbias, flags, meta, top_i, top_p);
    route_pack<<<1, RP_T, 0, stream>>>(top_i, meta, atok, ainv);

    // ---- ablation probes (idempotent, no output) ----
    eg1_probe_stage<<<dim3(F_FF / 256, N_TOK / 256, N_EXP), 512, 131072, stream>>>(
        xh, W1T, meta, atok);
    eg1_probe_mfma<<<dim3(F_FF / 256, N_TOK / 256, N_EXP), 512, 131072, stream>>>(
        xh, W1T, meta, atok);

    expert_gemm1<<<dim3(F_FF / 256, N_TOK / 256, N_EXP), 512, 131072, stream>>>(
        xh, W1T, b1, meta, atok, actb);
    expert_gemm2<<<dim3(D_MODEL / 256, N_TOK / 256, N_EXP), 512, 131072, stream>>>(
        actb, W2T, b2, meta, eo);
    combine_kernel<<<N_TOK, 256, 0, stream>>>(eo, ainv, top_p, out);
}

// Round 4
// 566.408 us; speedup vs baseline: 1.1542x; 1.1542x over previous
//
#include <hip/hip_runtime.h>
#include <hip/hip_bf16.h>
#include <stdint.h>

typedef __bf16 bf16;
typedef bf16 bf16x8 __attribute__((ext_vector_type(8)));
typedef bf16 bf16x4 __attribute__((ext_vector_type(4)));
typedef float f32x4 __attribute__((ext_vector_type(4)));
typedef int i32x4 __attribute__((ext_vector_type(4)));

#define N_TOK 8192
#define D_MODEL 1024
#define H_R 512
#define N_EXP 6
#define F_FF 1536
#define FLAG_CAP 1024

// Abramowitz-Stegun 7.1.26: |err| <= 1.5e-7
__device__ __forceinline__ float erf_fast(float x) {
    float ax = fabsf(x);
    float t = 1.0f / (1.0f + 0.3275911f * ax);
    float p = t * (0.254829592f + t * (-0.284496736f + t * (1.421413741f +
              t * (-1.453152027f + t * 1.061405429f))));
    float r = 1.0f - p * __expf(-ax * ax);
    return copysignf(r, x);
}
__device__ __forceinline__ float gelu_f(float x) {
    return 0.5f * x * (1.0f + erf_fast(x * 0.70710678118654752f));
}
__device__ __forceinline__ float silu_f(float x) {
    return x * (1.0f / (1.0f + __expf(-x)));
}

typedef __attribute__((address_space(1))) const void* gas1;
typedef __attribute__((address_space(3))) void* las3;

__device__ __forceinline__ void gload16(const void* g, void* l) {
    __builtin_amdgcn_global_load_lds((gas1)g, (las3)l, 16, 0, 0);
}

// LDS chunk swizzle for the 128x128 router core: row r's logical 16B chunk q
// lives at chunk-slot (q + (r>>1)) & 3.
__device__ __forceinline__ int swz_src_q(int c) {
    return (((c & 3) - ((c >> 2) >> 1)) & 3);
}

#define GATE(N) asm volatile("s_waitcnt vmcnt(" #N ")\n\ts_barrier" ::: "memory")

// ---------------- conversion / transpose ------------------------------------

__global__ __launch_bounds__(256) void convert_x_split(
    const float* __restrict__ x, bf16* __restrict__ xh, bf16* __restrict__ xl) {
    size_t i = ((size_t)blockIdx.x * 256 + threadIdx.x) * 8;
    f32x4 a = *(const f32x4*)(x + i);
    f32x4 b = *(const f32x4*)(x + i + 4);
    float v[8] = {a[0], a[1], a[2], a[3], b[0], b[1], b[2], b[3]};
    bf16x8 vh, vl;
    #pragma unroll
    for (int k = 0; k < 8; ++k) {
        bf16 h = (bf16)v[k];
        vh[k] = h;
        vl[k] = (bf16)(v[k] - (float)h);
    }
    *(bf16x8*)(xh + i) = vh;
    *(bf16x8*)(xl + i) = vl;
}

__global__ __launch_bounds__(256) void transpose_bf16_64(
    const float* __restrict__ in, bf16* __restrict__ out, int R, int C) {
    __shared__ float tile[64][65];
    const float* inp = in + (size_t)blockIdx.z * R * C;
    bf16* op = out + (size_t)blockIdx.z * R * C;
    int tx = threadIdx.x & 15, ty = threadIdx.x >> 4;
    int r0 = blockIdx.y * 64, c0 = blockIdx.x * 64;
    #pragma unroll
    for (int p = 0; p < 4; ++p) {
        int row = p * 16 + ty;
        f32x4 v = *(const f32x4*)(inp + (size_t)(r0 + row) * C + c0 + tx * 4);
        tile[row][tx * 4 + 0] = v[0];
        tile[row][tx * 4 + 1] = v[1];
        tile[row][tx * 4 + 2] = v[2];
        tile[row][tx * 4 + 3] = v[3];
    }
    __syncthreads();
    #pragma unroll
    for (int p = 0; p < 4; ++p) {
        int cc = p * 16 + ty;
        bf16x4 o;
        #pragma unroll
        for (int k = 0; k < 4; ++k) o[k] = (bf16)tile[tx * 4 + k][cc];
        *(bf16x4*)(op + (size_t)(c0 + cc) * R + r0 + tx * 4) = o;
    }
}

__global__ __launch_bounds__(256) void transpose_split(
    const float* __restrict__ in, bf16* __restrict__ oh, bf16* __restrict__ ol,
    int R, int C) {
    __shared__ float tile[32][33];
    int tx = threadIdx.x & 31, ty = threadIdx.x >> 5;
    int r0 = blockIdx.y * 32, c0 = blockIdx.x * 32;
    #pragma unroll
    for (int yy = ty; yy < 32; yy += 8)
        tile[yy][tx] = in[(size_t)(r0 + yy) * C + c0 + tx];
    __syncthreads();
    #pragma unroll
    for (int yy = ty; yy < 32; yy += 8) {
        float v = tile[tx][yy];
        bf16 h = (bf16)v;
        size_t o = (size_t)(c0 + yy) * R + r0 + tx;
        oh[o] = h;
        ol[o] = (bf16)(v - (float)h);
    }
}

// ---------------- 128x128 bf16 MFMA GEMM core (router path) -----------------

struct SMemStd {
    alignas(16) bf16 As[128 * 32];
    alignas(16) bf16 Bs[128 * 32];
};

__device__ __forceinline__ void gemm_core_async(
    const bf16* gA0, const bf16* gA1, const bf16* gB0, const bf16* gB1,
    int K, bf16* As, bf16* Bs, f32x4 acc[4][4]) {
    const int tid = threadIdx.x;
    const int lane = tid & 63;
    const int w = tid >> 6;
    const int wm = w & 1, wn = w >> 1;
    const int lc = lane & 15;
    const int koff = ((((lane >> 4) + (lc >> 1)) & 3) * 8);
    bf16* lA0 = As + w * 512;
    bf16* lA1 = As + 2048 + w * 512;
    bf16* lB0 = Bs + w * 512;
    bf16* lB1 = Bs + 2048 + w * 512;
    for (int kb = 0; kb < K; kb += 32) {
        __syncthreads();
        gload16(gA0 + kb, lA0);
        gload16(gA1 + kb, lA1);
        gload16(gB0 + kb, lB0);
        gload16(gB1 + kb, lB1);
        __syncthreads();
        bf16x8 af[4], bfr[4];
        #pragma unroll
        for (int i = 0; i < 4; ++i)
            af[i] = *(const bf16x8*)(As + (wm * 64 + i * 16 + lc) * 32 + koff);
        #pragma unroll
        for (int j = 0; j < 4; ++j)
            bfr[j] = *(const bf16x8*)(Bs + (wn * 64 + j * 16 + lc) * 32 + koff);
        #pragma unroll
        for (int i = 0; i < 4; ++i)
            #pragma unroll
            for (int j = 0; j < 4; ++j)
                acc[i][j] = __builtin_amdgcn_mfma_f32_16x16x32_bf16(af[i], bfr[j], acc[i][j], 0, 0, 0);
    }
}

// ---------------- 128x128 BK=64 double-buffered core (expert path) ----------
// 256 threads = 4 waves (2M x 2N); wave tile 64x64; LDS 64 KiB static ->
// 2 blocks/CU co-resident. Per K-tile: issue loads(t+1) -> ds_read 16 frags
// -> 32 MFMA -> GATE(0) (loads t+1 landed + WAR barrier). The vmcnt drain
// and barrier skew are hidden by the co-resident block (m114 mechanism),
// not by intra-block lockstep phasing.
// LDS layout (bf16 elems): A0 [0,8K) B0 [8K,16K) A1 [16K,24K) B1 [24K,32K).
// Chunk swizzle: row r's logical 16B chunk q at phys chunk (q+r)&7, applied
// via pre-swizzled global source + swizzled ds_read (both-sides, rule #21).

__device__ __forceinline__ void gemm128_core(
    const bf16* ap0, const bf16* ap1, const bf16* ap2, const bf16* ap3,
    const bf16* bp0, const bf16* bp1, const bf16* bp2, const bf16* bp3,
    int K, bf16* As, bf16* Bs, f32x4 acc[4][4])
{
    const int tid = threadIdx.x;
    const int w = tid >> 6;
    const int lane = tid & 63;
    const int lc = lane & 15, qdv = lane >> 4;
    const int wm = w & 1, wn = w >> 1;
    const int wst = w * 512;            // per-wave staging offset (elems)
    const int NT = K >> 6;
    // prologue: stage tile 0 into buf 0 (4 passes x 32 rows each for A and B)
    gload16(ap0, As + wst);
    gload16(ap1, As + 2048 + wst);
    gload16(ap2, As + 4096 + wst);
    gload16(ap3, As + 6144 + wst);
    gload16(bp0, Bs + wst);
    gload16(bp1, Bs + 2048 + wst);
    gload16(bp2, Bs + 4096 + wst);
    gload16(bp3, Bs + 6144 + wst);
    ap0 += 64; ap1 += 64; ap2 += 64; ap3 += 64;
    bp0 += 64; bp1 += 64; bp2 += 64; bp3 += 64;
    GATE(0);
    const int rA0 = wm * 64 + lc;
    const int rB0 = wn * 64 + lc;
    int bo = 0;
    for (int t = 0; t < NT; ++t) {
        const int nb = bo ^ 16384;
        const bool pref = (t + 1 < NT);
        if (pref) {
            gload16(ap0, As + nb + wst);
            gload16(ap1, As + nb + 2048 + wst);
            gload16(ap2, As + nb + 4096 + wst);
            gload16(ap3, As + nb + 6144 + wst);
            gload16(bp0, Bs + nb + wst);
            gload16(bp1, Bs + nb + 2048 + wst);
            gload16(bp2, Bs + nb + 4096 + wst);
            gload16(bp3, Bs + nb + 6144 + wst);
            ap0 += 64; ap1 += 64; ap2 += 64; ap3 += 64;
            bp0 += 64; bp1 += 64; bp2 += 64; bp3 += 64;
        }
        bf16x8 af[4][2], bfr[4][2];
        #pragma unroll
        for (int i = 0; i < 4; ++i) {
            int row = rA0 + i * 16;
            #pragma unroll
            for (int s = 0; s < 2; ++s)
                af[i][s] = *(const bf16x8*)(As + bo + row * 64 + (((s * 4 + qdv) + row) & 7) * 8);
        }
        #pragma unroll
        for (int j = 0; j < 4; ++j) {
            int row = rB0 + j * 16;
            #pragma unroll
            for (int s = 0; s < 2; ++s)
                bfr[j][s] = *(const bf16x8*)(Bs + bo + row * 64 + (((s * 4 + qdv) + row) & 7) * 8);
        }
        __builtin_amdgcn_s_setprio(1);
        #pragma unroll
        for (int i = 0; i < 4; ++i)
            #pragma unroll
            for (int j = 0; j < 4; ++j)
                #pragma unroll
                for (int s = 0; s < 2; ++s)
                    acc[i][j] = __builtin_amdgcn_mfma_f32_16x16x32_bf16(af[i][s], bfr[j][s], acc[i][j], 0, 0, 0);
        __builtin_amdgcn_s_setprio(0);
        if (pref) GATE(0);   // loads(t+1) landed; WAR release for next issue
        bo = nb;
    }
}

// ---------------- router GEMM1: z-split 3-term (fp32-accurate sum) ----------

__global__ __launch_bounds__(256) void router_gemm1_3(
    const bf16* __restrict__ xh, const bf16* __restrict__ xl,
    const bf16* __restrict__ wTh, const bf16* __restrict__ wTl,
    float* __restrict__ hp0, float* __restrict__ hp1, float* __restrict__ hp2) {
    __shared__ SMemStd sm;
    const int z = blockIdx.z;
    const bf16* Ab = (z == 2) ? xl : xh;
    const bf16* Bb = (z == 1) ? wTl : wTh;
    float* hp = (z == 0) ? hp0 : (z == 1 ? hp1 : hp2);
    const int tid = threadIdx.x;
    const int mbase = blockIdx.y * 128, nbase = blockIdx.x * 128;
    int c0 = tid, c1 = tid + 256;
    const bf16* gA0 = Ab + (size_t)(mbase + (c0 >> 2)) * D_MODEL + swz_src_q(c0) * 8;
    const bf16* gA1 = Ab + (size_t)(mbase + (c1 >> 2)) * D_MODEL + swz_src_q(c1) * 8;
    const bf16* Bt = Bb + (size_t)nbase * D_MODEL;
    const bf16* gB0 = Bt + (size_t)(c0 >> 2) * D_MODEL + swz_src_q(c0) * 8;
    const bf16* gB1 = Bt + (size_t)(c1 >> 2) * D_MODEL + swz_src_q(c1) * 8;
    f32x4 acc[4][4] = {};
    gemm_core_async(gA0, gA1, gB0, gB1, D_MODEL, sm.As, sm.Bs, acc);
    const int lane = tid & 63;
    const int w = tid >> 6;
    const int wm = w & 1, wn = w >> 1;
    const int lc = lane & 15, quad = lane >> 4;
    #pragma unroll
    for (int i = 0; i < 4; ++i)
        #pragma unroll
        for (int j = 0; j < 4; ++j) {
            int col = nbase + wn * 64 + j * 16 + lc;
            #pragma unroll
            for (int r = 0; r < 4; ++r) {
                int row = mbase + wm * 64 + i * 16 + quad * 4 + r;
                hp[(size_t)row * H_R + col] = acc[i][j][r];
            }
        }
}

// ---------------- fused LayerNorm + GELU + logits + top-2 -------------------

__global__ __launch_bounds__(256) void ln_router2(
    const float* __restrict__ hp0, const float* __restrict__ hp1,
    const float* __restrict__ hp2, const float* __restrict__ r1b,
    const float* __restrict__ g, const float* __restrict__ bta,
    const float* __restrict__ r2w, const float* __restrict__ r2b,
    const float* __restrict__ temp, const float* __restrict__ rbias,
    int* __restrict__ top_i, float* __restrict__ top_p,
    int* __restrict__ flaglist, int* __restrict__ meta) {
    __shared__ float Wl[H_R * N_EXP];
    int tid = threadIdx.x;
    for (int i = tid; i < H_R * N_EXP; i += 256) Wl[i] = r2w[i];
    __syncthreads();
    int w = tid >> 6, lane = tid & 63;
    int t = blockIdx.x * 4 + w;
    size_t rbase = (size_t)t * H_R;
    int k0 = lane * 8;
    float v[8];
    {
        f32x4 a0 = *(const f32x4*)(hp0 + rbase + k0);
        f32x4 a1 = *(const f32x4*)(hp0 + rbase + k0 + 4);
        f32x4 b0 = *(const f32x4*)(hp1 + rbase + k0);
        f32x4 b1 = *(const f32x4*)(hp1 + rbase + k0 + 4);
        f32x4 c0 = *(const f32x4*)(hp2 + rbase + k0);
        f32x4 c1 = *(const f32x4*)(hp2 + rbase + k0 + 4);
        f32x4 d0 = *(const f32x4*)(r1b + k0);
        f32x4 d1 = *(const f32x4*)(r1b + k0 + 4);
        #pragma unroll
        for (int k = 0; k < 4; ++k) {
            v[k]     = a0[k] + b0[k] + c0[k] + d0[k];
            v[k + 4] = a1[k] + b1[k] + c1[k] + d1[k];
        }
    }
    float s = 0.f;
    #pragma unroll
    for (int k = 0; k < 8; ++k) s += v[k];
    #pragma unroll
    for (int off = 32; off; off >>= 1) s += __shfl_xor(s, off);
    float mu = s * (1.0f / H_R);
    float q = 0.f;
    #pragma unroll
    for (int k = 0; k < 8; ++k) { float d = v[k] - mu; q += d * d; }
    #pragma unroll
    for (int off = 32; off; off >>= 1) q += __shfl_xor(q, off);
    float scl = 1.0f / sqrtf(q * (1.0f / H_R) + 1e-5f);
    f32x4 g0 = *(const f32x4*)(g + k0), g1 = *(const f32x4*)(g + k0 + 4);
    f32x4 b0 = *(const f32x4*)(bta + k0), b1v = *(const f32x4*)(bta + k0 + 4);
    float G[8] = {g0[0], g0[1], g0[2], g0[3], g1[0], g1[1], g1[2], g1[3]};
    float B[8] = {b0[0], b0[1], b0[2], b0[3], b1v[0], b1v[1], b1v[2], b1v[3]};
    float acc[N_EXP] = {};
    #pragma unroll
    for (int k = 0; k < 8; ++k) {
        float y = gelu_f((v[k] - mu) * scl * G[k] + B[k]);
        const float* wr = &Wl[(k0 + k) * N_EXP];
        #pragma unroll
        for (int e = 0; e < N_EXP; ++e) acc[e] += y * wr[e];
    }
    #pragma unroll
    for (int e = 0; e < N_EXP; ++e)
        #pragma unroll
        for (int off = 32; off; off >>= 1) acc[e] += __shfl_xor(acc[e], off);
    if (lane == 0) {
        float tinv = 1.0f / temp[0];
        float lg[N_EXP];
        #pragma unroll
        for (int e = 0; e < N_EXP; ++e) lg[e] = (acc[e] + r2b[e]) * tinv + rbias[e];
        float v1 = -1e30f; int i1 = 0;
        #pragma unroll
        for (int e = 0; e < N_EXP; ++e) if (lg[e] > v1) { v1 = lg[e]; i1 = e; }
        float v2 = -1e30f; int i2 = 0;
        #pragma unroll
        for (int e = 0; e < N_EXP; ++e) if (e != i1 && lg[e] > v2) { v2 = lg[e]; i2 = e; }
        float v3 = -1e30f;
        #pragma unroll
        for (int e = 0; e < N_EXP; ++e) if (e != i1 && e != i2 && lg[e] > v3) v3 = lg[e];
        float ssum = 0.f;
        #pragma unroll
        for (int e = 0; e < N_EXP; ++e) ssum += __expf(lg[e] - v1);
        float inv = 1.0f / ssum;
        top_i[2 * t] = i1; top_i[2 * t + 1] = i2;
        top_p[2 * t] = inv;
        top_p[2 * t + 1] = __expf(v2 - v1) * inv;
        if (v2 - v3 < 1e-3f) {
            int ix = atomicAdd(&meta[24], 1);
            if (ix < FLAG_CAP) flaglist[ix] = t;
        }
    }
}

// ---------------- fp64 exact rescue for near-tie tokens ---------------------

__global__ __launch_bounds__(256) void router_rescue(
    const float* __restrict__ x, const float* __restrict__ r1w,
    const float* __restrict__ r1b, const float* __restrict__ lng,
    const float* __restrict__ lnb, const float* __restrict__ r2w,
    const float* __restrict__ r2b, const float* __restrict__ temp,
    const float* __restrict__ rbias, const int* __restrict__ flaglist,
    const int* __restrict__ meta, int* __restrict__ top_i, float* __restrict__ top_p) {
    int n = meta[24]; if (n > FLAG_CAP) n = FLAG_CAP;
    if ((int)blockIdx.x >= n) return;
    int t = flaglist[blockIdx.x];
    __shared__ double xs[D_MODEL];
    __shared__ double hbuf[H_R];
    __shared__ double red[8];
    int tid = threadIdx.x;
    for (int k = tid; k < D_MODEL; k += 256) xs[k] = (double)x[(size_t)t * D_MODEL + k];
    __syncthreads();
    for (int c = tid; c < H_R; c += 256) {
        double s = 0.0;
        for (int k = 0; k < D_MODEL; ++k) s += xs[k] * (double)r1w[(size_t)k * H_R + c];
        hbuf[c] = s + (double)r1b[c];
    }
    __syncthreads();
    double ls = 0.0;
    for (int c = tid; c < H_R; c += 256) ls += hbuf[c];
    #pragma unroll
    for (int off = 32; off; off >>= 1) ls += __shfl_xor(ls, off);
    if ((tid & 63) == 0) red[tid >> 6] = ls;
    __syncthreads();
    double mu = (red[0] + red[1] + red[2] + red[3]) * (1.0 / H_R);
    __syncthreads();
    double q = 0.0;
    for (int c = tid; c < H_R; c += 256) { double d = hbuf[c] - mu; q += d * d; }
    #pragma unroll
    for (int off = 32; off; off >>= 1) q += __shfl_xor(q, off);
    if ((tid & 63) == 0) red[tid >> 6] = q;
    __syncthreads();
    double var = (red[0] + red[1] + red[2] + red[3]) * (1.0 / H_R);
    double scl = 1.0 / sqrt(var + 1e-5);
    __syncthreads();
    for (int c = tid; c < H_R; c += 256) {
        double y = (hbuf[c] - mu) * scl * (double)lng[c] + (double)lnb[c];
        hbuf[c] = 0.5 * y * (1.0 + erf(y * 0.70710678118654752440));
    }
    __syncthreads();
    if (tid < N_EXP) {
        double s = 0.0;
        for (int k = 0; k < H_R; ++k) s += hbuf[k] * (double)r2w[k * N_EXP + tid];
        red[tid] = (s + (double)r2b[tid]) / (double)temp[0] + (double)rbias[tid];
    }
    __syncthreads();
    if (tid == 0) {
        double lg[N_EXP];
        #pragma unroll
        for (int e = 0; e < N_EXP; ++e) lg[e] = red[e];
        double v1 = -1e300; int i1 = 0;
        for (int e = 0; e < N_EXP; ++e) if (lg[e] > v1) { v1 = lg[e]; i1 = e; }
        double v2 = -1e300; int i2 = 0;
        for (int e = 0; e < N_EXP; ++e) if (e != i1 && lg[e] > v2) { v2 = lg[e]; i2 = e; }
        double s = 0.0;
        for (int e = 0; e < N_EXP; ++e) s += exp(lg[e] - v1);
        double inv = 1.0 / s;
        top_i[2 * t] = i1; top_i[2 * t + 1] = i2;
        top_p[2 * t] = (float)inv;
        top_p[2 * t + 1] = (float)(exp(v2 - v1) * inv);
    }
}

// ---------------- route_pack: count + scan + scatter, zero global atomics ---

#define RP_T 1024
#define RP_TOK (N_TOK / RP_T)   // 8 tokens per thread

__global__ __launch_bounds__(1024) void route_pack(
    const int* __restrict__ top_i, int* __restrict__ meta,
    int* __restrict__ atok, int* __restrict__ ainv) {
    __shared__ int S[N_EXP][RP_T];
    __shared__ int segbase[N_EXP + 1];
    int tid = threadIdx.x;
    int e_loc[2 * RP_TOK];
    int cnt[N_EXP];
    #pragma unroll
    for (int e = 0; e < N_EXP; ++e) cnt[e] = 0;
    int t0 = tid * RP_TOK;
    #pragma unroll
    for (int q = 0; q < (2 * RP_TOK) / 4; ++q) {
        i32x4 v = *(const i32x4*)(top_i + 2 * t0 + q * 4);
        #pragma unroll
        for (int k = 0; k < 4; ++k) {
            int e = v[k];
            e_loc[q * 4 + k] = e;
            #pragma unroll
            for (int ee = 0; ee < N_EXP; ++ee) if (e == ee) cnt[ee]++;
        }
    }
    #pragma unroll
    for (int e = 0; e < N_EXP; ++e) S[e][tid] = cnt[e];
    __syncthreads();
    for (int off = 1; off < RP_T; off <<= 1) {
        int tmp[N_EXP];
        #pragma unroll
        for (int e = 0; e < N_EXP; ++e)
            tmp[e] = (tid >= off) ? S[e][tid - off] : 0;
        __syncthreads();
        #pragma unroll
        for (int e = 0; e < N_EXP; ++e) S[e][tid] += tmp[e];
        __syncthreads();
    }
    if (tid == 0) {
        int o = 0;
        #pragma unroll
        for (int e = 0; e < N_EXP; ++e) {
            segbase[e] = o;
            int tot = S[e][RP_T - 1];
            meta[e] = tot;
            meta[8 + e] = o;
            o += tot;
        }
        segbase[N_EXP] = o;
    }
    __syncthreads();
    int pos[N_EXP];
    #pragma unroll
    for (int e = 0; e < N_EXP; ++e)
        pos[e] = segbase[e] + S[e][tid] - cnt[e];
    #pragma unroll
    for (int k = 0; k < 2 * RP_TOK; ++k) {
        int e = e_loc[k];
        int a = 0;
        #pragma unroll
        for (int ee = 0; ee < N_EXP; ++ee) if (e == ee) a = pos[ee]++;
        atok[a] = t0 + (k >> 1);
        ainv[2 * t0 + k] = a;
    }
}

// ---------------- expert GEMMs: 128x128 BK=64, 2 blocks/CU ------------------

__global__ __launch_bounds__(256) void expert_gemm1(
    const bf16* __restrict__ xb, const bf16* __restrict__ W1T,
    const float* __restrict__ b1, const int* __restrict__ meta,
    const int* __restrict__ atok, bf16* __restrict__ act) {
    __shared__ bf16 smem[32768];           // 64 KiB: A0 B0 A1 B1 (8K elems each)
    int e = blockIdx.z;
    int rows = meta[e];
    int mloc = blockIdx.y * 128;
    if (mloc >= rows) return;
    int base = meta[8 + e];
    int tid = threadIdx.x;
    int nbase = blockIdx.x * 128;
    const int sr = tid >> 3;               // staging row within 32-row pass
    const int sc = tid & 7;                // phys 16B chunk
    const bf16* ap[4];
    const bf16* bp[4];
    #pragma unroll
    for (int h = 0; h < 4; ++h) {
        int tr = h * 32 + sr;              // tile-local row 0..127
        int q = (sc - tr) & 7;             // logical chunk for this phys slot
        int rr = mloc + tr; if (rr > rows - 1) rr = rows - 1;
        ap[h] = xb + (size_t)atok[base + rr] * D_MODEL + q * 8;
        bp[h] = W1T + ((size_t)e * F_FF + nbase + tr) * D_MODEL + q * 8;
    }
    f32x4 acc[4][4] = {};
    gemm128_core(ap[0], ap[1], ap[2], ap[3], bp[0], bp[1], bp[2], bp[3],
                 D_MODEL, smem, smem + 8192, acc);
    const int lane = tid & 63;
    const int w = tid >> 6;
    const int wm = w & 1, wn = w >> 1;
    const int lc = lane & 15, qd = lane >> 4;
    const bool oddE = (e & 1) != 0;
    #pragma unroll
    for (int i = 0; i < 4; ++i) {
        #pragma unroll
        for (int j = 0; j < 4; ++j) {
            int col = nbase + wn * 64 + j * 16 + lc;
            float bias = b1[e * F_FF + col];
            #pragma unroll
            for (int r = 0; r < 4; ++r) {
                int rloc = mloc + wm * 64 + i * 16 + qd * 4 + r;
                if (rloc < rows) {
                    float vv = acc[i][j][r] + bias;
                    vv = oddE ? silu_f(vv) : gelu_f(vv);
                    act[(size_t)(base + rloc) * F_FF + col] = (bf16)vv;
                }
            }
        }
    }
}

__global__ __launch_bounds__(256) void expert_gemm2(
    const bf16* __restrict__ act, const bf16* __restrict__ W2T,
    const float* __restrict__ b2, const int* __restrict__ meta,
    float* __restrict__ eo) {
    __shared__ bf16 smem[32768];
    int e = blockIdx.z;
    int rows = meta[e];
    int mloc = blockIdx.y * 128;
    if (mloc >= rows) return;
    int base = meta[8 + e];
    int tid = threadIdx.x;
    int nbase = blockIdx.x * 128;
    const int sr = tid >> 3;
    const int sc = tid & 7;
    const bf16* ap[4];
    const bf16* bp[4];
    #pragma unroll
    for (int h = 0; h < 4; ++h) {
        int tr = h * 32 + sr;
        int q = (sc - tr) & 7;
        int rr = mloc + tr; if (rr > rows - 1) rr = rows - 1;
        ap[h] = act + (size_t)(base + rr) * F_FF + q * 8;
        bp[h] = W2T + ((size_t)e * D_MODEL + nbase + tr) * F_FF + q * 8;
    }
    f32x4 acc[4][4] = {};
    gemm128_core(ap[0], ap[1], ap[2], ap[3], bp[0], bp[1], bp[2], bp[3],
                 F_FF, smem, smem + 8192, acc);
    const int lane = tid & 63;
    const int w = tid >> 6;
    const int wm = w & 1, wn = w >> 1;
    const int lc = lane & 15, qd = lane >> 4;
    #pragma unroll
    for (int i = 0; i < 4; ++i) {
        #pragma unroll
        for (int j = 0; j < 4; ++j) {
            int col = nbase + wn * 64 + j * 16 + lc;
            float bias = b2[e * D_MODEL + col];
            #pragma unroll
            for (int r = 0; r < 4; ++r) {
                int rloc = mloc + wm * 64 + i * 16 + qd * 4 + r;
                if (rloc < rows)
                    eo[(size_t)(base + rloc) * D_MODEL + col] = acc[i][j][r] + bias;
            }
        }
    }
}

// ---------------- weighted combine ------------------------------------------

__global__ __launch_bounds__(256) void combine_kernel(
    const float* __restrict__ eo, const int* __restrict__ ainv,
    const float* __restrict__ top_p, float* __restrict__ out) {
    int t = blockIdx.x;
    int s0 = ainv[2 * t], s1 = ainv[2 * t + 1];
    float p0 = top_p[2 * t], p1 = top_p[2 * t + 1];
    int c = threadIdx.x * 4;
    f32x4 a = *(const f32x4*)(eo + (size_t)s0 * D_MODEL + c);
    f32x4 b = *(const f32x4*)(eo + (size_t)s1 * D_MODEL + c);
    f32x4 o;
    #pragma unroll
    for (int k = 0; k < 4; ++k) o[k] = a[k] * p0 + b[k] * p1;
    *(f32x4*)(out + (size_t)t * D_MODEL + c) = o;
}

// ---------------- launch ----------------------------------------------------

extern "C" void kernel_launch(void* const* d_in, const int* in_sizes, int n_in,
                              void* d_out, int out_size, void* d_ws, size_t ws_size,
                              hipStream_t stream) {
    const float* x     = (const float*)d_in[0];
    const float* r1w   = (const float*)d_in[1];
    const float* r1b   = (const float*)d_in[2];
    const float* lng   = (const float*)d_in[3];
    const float* lnb   = (const float*)d_in[4];
    const float* r2w   = (const float*)d_in[5];
    const float* r2b   = (const float*)d_in[6];
    const float* temp  = (const float*)d_in[7];
    const float* rbias = (const float*)d_in[8];
    const float* W1    = (const float*)d_in[9];
    const float* b1    = (const float*)d_in[10];
    const float* W2    = (const float*)d_in[11];
    const float* b2    = (const float*)d_in[12];
    float* out = (float*)d_out;

    char* ws = (char*)d_ws;
    size_t off = 0;
    auto alloc = [&](size_t bytes) -> void* {
        void* p = ws + off;
        off = (off + bytes + 255) & ~(size_t)255;
        return p;
    };
    bf16*  xh    = (bf16*)alloc((size_t)N_TOK * D_MODEL * 2);
    bf16*  xl    = (bf16*)alloc((size_t)N_TOK * D_MODEL * 2);
    bf16*  r1wTh = (bf16*)alloc((size_t)H_R * D_MODEL * 2);
    bf16*  r1wTl = (bf16*)alloc((size_t)H_R * D_MODEL * 2);
    bf16*  W1T   = (bf16*)alloc((size_t)N_EXP * F_FF * D_MODEL * 2);
    bf16*  W2T   = (bf16*)alloc((size_t)N_EXP * D_MODEL * F_FF * 2);
    float* hp0   = (float*)alloc((size_t)N_TOK * H_R * 4);
    int*   top_i = (int*)alloc((size_t)N_TOK * 2 * 4);
    float* top_p = (float*)alloc((size_t)N_TOK * 2 * 4);
    int*   meta  = (int*)alloc(256);
    int*   flags = (int*)alloc(FLAG_CAP * 4);
    int*   atok  = (int*)alloc((size_t)2 * N_TOK * 4);
    int*   ainv  = (int*)alloc((size_t)2 * N_TOK * 4);
    bf16*  actb  = (bf16*)alloc((size_t)2 * N_TOK * F_FF * 2);
    float* eo    = (float*)alloc((size_t)2 * N_TOK * D_MODEL * 4);
    float* hp1 = (float*)actb;
    float* hp2 = (float*)((char*)actb + (size_t)N_TOK * H_R * 4);
    (void)ws_size; (void)n_in; (void)in_sizes;

    hipMemsetAsync(meta, 0, 256, stream);

    convert_x_split<<<(N_TOK * D_MODEL) / (256 * 8), 256, 0, stream>>>(x, xh, xl);
    transpose_split<<<dim3(H_R / 32, D_MODEL / 32, 1), 256, 0, stream>>>(
        r1w, r1wTh, r1wTl, D_MODEL, H_R);
    transpose_bf16_64<<<dim3(F_FF / 64, D_MODEL / 64, N_EXP), 256, 0, stream>>>(
        W1, W1T, D_MODEL, F_FF);
    transpose_bf16_64<<<dim3(D_MODEL / 64, F_FF / 64, N_EXP), 256, 0, stream>>>(
        W2, W2T, F_FF, D_MODEL);

    router_gemm1_3<<<dim3(H_R / 128, N_TOK / 128, 3), 256, 0, stream>>>(
        xh, xl, r1wTh, r1wTl, hp0, hp1, hp2);
    ln_router2<<<N_TOK / 4, 256, 0, stream>>>(
        hp0, hp1, hp2, r1b, lng, lnb, r2w, r2b, temp, rbias, top_i, top_p, flags, meta);
    router_rescue<<<FLAG_CAP, 256, 0, stream>>>(
        x, r1w, r1b, lng, lnb, r2w, r2b, temp, rbias, flags, meta, top_i, top_p);
    route_pack<<<1, RP_T, 0, stream>>>(top_i, meta, atok, ainv);

    expert_gemm1<<<dim3(F_FF / 128, N_TOK / 128, N_EXP), 256, 0, stream>>>(
        xh, W1T, b1, meta, atok, actb);
    expert_gemm2<<<dim3(D_MODEL / 128, N_TOK / 128, N_EXP), 256, 0, stream>>>(
        actb, W2T, b2, meta, eo);
    combine_kernel<<<N_TOK, 256, 0, stream>>>(eo, ainv, top_p, out);
}

// Round 5
// 537.371 us; speedup vs baseline: 1.2166x; 1.0540x over previous
//
#include <hip/hip_runtime.h>
#include <hip/hip_bf16.h>
#include <stdint.h>

typedef __bf16 bf16;
typedef bf16 bf16x8 __attribute__((ext_vector_type(8)));
typedef bf16 bf16x4 __attribute__((ext_vector_type(4)));
typedef float f32x4 __attribute__((ext_vector_type(4)));
typedef int i32x4 __attribute__((ext_vector_type(4)));

#define N_TOK 8192
#define D_MODEL 1024
#define H_R 512
#define N_EXP 6
#define F_FF 1536
#define FLAG_CAP 1024

// Abramowitz-Stegun 7.1.26: |err| <= 1.5e-7
__device__ __forceinline__ float erf_fast(float x) {
    float ax = fabsf(x);
    float t = 1.0f / (1.0f + 0.3275911f * ax);
    float p = t * (0.254829592f + t * (-0.284496736f + t * (1.421413741f +
              t * (-1.453152027f + t * 1.061405429f))));
    float r = 1.0f - p * __expf(-ax * ax);
    return copysignf(r, x);
}
__device__ __forceinline__ float gelu_f(float x) {
    return 0.5f * x * (1.0f + erf_fast(x * 0.70710678118654752f));
}
__device__ __forceinline__ float silu_f(float x) {
    return x * (1.0f / (1.0f + __expf(-x)));
}

typedef __attribute__((address_space(1))) const void* gas1;
typedef __attribute__((address_space(3))) void* las3;

__device__ __forceinline__ void gload16(const void* g, void* l) {
    __builtin_amdgcn_global_load_lds((gas1)g, (las3)l, 16, 0, 0);
}

// LDS chunk swizzle (verified, round 0): row r's logical 16B chunk q lives at
// chunk-slot (q + (r>>1)) & 3. Source-side inverse:
__device__ __forceinline__ int swz_src_q(int c) {
    return (((c & 3) - ((c >> 2) >> 1)) & 3);
}

// counted waitcnt + barrier release point; "memory" clobber pins ds_reads below
#define GATE(N) asm volatile("s_waitcnt vmcnt(" #N ")\n\ts_barrier" ::: "memory")

// ---------------- conversion / transpose ------------------------------------

__global__ __launch_bounds__(256) void convert_x_split(
    const float* __restrict__ x, bf16* __restrict__ xh, bf16* __restrict__ xl) {
    size_t i = ((size_t)blockIdx.x * 256 + threadIdx.x) * 8;
    f32x4 a = *(const f32x4*)(x + i);
    f32x4 b = *(const f32x4*)(x + i + 4);
    float v[8] = {a[0], a[1], a[2], a[3], b[0], b[1], b[2], b[3]};
    bf16x8 vh, vl;
    #pragma unroll
    for (int k = 0; k < 8; ++k) {
        bf16 h = (bf16)v[k];
        vh[k] = h;
        vl[k] = (bf16)(v[k] - (float)h);
    }
    *(bf16x8*)(xh + i) = vh;
    *(bf16x8*)(xl + i) = vl;
}

__global__ __launch_bounds__(256) void transpose_bf16_64(
    const float* __restrict__ in, bf16* __restrict__ out, int R, int C) {
    __shared__ float tile[64][65];
    const float* inp = in + (size_t)blockIdx.z * R * C;
    bf16* op = out + (size_t)blockIdx.z * R * C;
    int tx = threadIdx.x & 15, ty = threadIdx.x >> 4;
    int r0 = blockIdx.y * 64, c0 = blockIdx.x * 64;
    #pragma unroll
    for (int p = 0; p < 4; ++p) {
        int row = p * 16 + ty;
        f32x4 v = *(const f32x4*)(inp + (size_t)(r0 + row) * C + c0 + tx * 4);
        tile[row][tx * 4 + 0] = v[0];
        tile[row][tx * 4 + 1] = v[1];
        tile[row][tx * 4 + 2] = v[2];
        tile[row][tx * 4 + 3] = v[3];
    }
    __syncthreads();
    #pragma unroll
    for (int p = 0; p < 4; ++p) {
        int cc = p * 16 + ty;
        bf16x4 o;
        #pragma unroll
        for (int k = 0; k < 4; ++k) o[k] = (bf16)tile[tx * 4 + k][cc];
        *(bf16x4*)(op + (size_t)(c0 + cc) * R + r0 + tx * 4) = o;
    }
}

__global__ __launch_bounds__(256) void transpose_split(
    const float* __restrict__ in, bf16* __restrict__ oh, bf16* __restrict__ ol,
    int R, int C) {
    __shared__ float tile[32][33];
    int tx = threadIdx.x & 31, ty = threadIdx.x >> 5;
    int r0 = blockIdx.y * 32, c0 = blockIdx.x * 32;
    #pragma unroll
    for (int yy = ty; yy < 32; yy += 8)
        tile[yy][tx] = in[(size_t)(r0 + yy) * C + c0 + tx];
    __syncthreads();
    #pragma unroll
    for (int yy = ty; yy < 32; yy += 8) {
        float v = tile[tx][yy];
        bf16 h = (bf16)v;
        size_t o = (size_t)(c0 + yy) * R + r0 + tx;
        oh[o] = h;
        ol[o] = (bf16)(v - (float)h);
    }
}

// ---------------- 128x128 BK=32 double-buffered core (expert path) ----------
// Round-0 verified addressing/swizzle + 32 KiB dbuf + counted GATE(4).
// 256 threads = 4 waves (2M x 2N). LDS 32 KiB -> with __launch_bounds__(256,4)
// 4 blocks/CU co-resident; staging latency hidden by TLP (m114 mechanism).
// LDS elems: [0,4K) A-buf0 [4K,8K) B-buf0 [8K,12K) A-buf1 [12K,16K) B-buf1.

__device__ __forceinline__ void gemm128_core(
    const bf16* gA0, const bf16* gA1, const bf16* gB0, const bf16* gB1,
    int K, bf16* sm, f32x4 acc[4][4])
{
    const int tid = threadIdx.x;
    const int lane = tid & 63;
    const int w = tid >> 6;
    const int wm = w & 1, wn = w >> 1;
    const int lc = lane & 15;
    const int koff = ((((lane >> 4) + (lc >> 1)) & 3) * 8);
    // prologue: stage tile 0 into buf 0
    gload16(gA0, sm + w * 512);
    gload16(gA1, sm + 2048 + w * 512);
    gload16(gB0, sm + 4096 + w * 512);
    gload16(gB1, sm + 6144 + w * 512);
    int bo = 0;
    const int NT = K >> 5;
    for (int t = 0; t < NT; ++t) {
        const int nb = bo ^ 8192;
        if (t + 1 < NT) {
            const int kb = (t + 1) << 5;
            gload16(gA0 + kb, sm + nb + w * 512);
            gload16(gA1 + kb, sm + nb + 2048 + w * 512);
            gload16(gB0 + kb, sm + nb + 4096 + w * 512);
            gload16(gB1 + kb, sm + nb + 6144 + w * 512);
            GATE(4);          // tile-t loads done; tile-(t+1) 4 stay in flight
        } else {
            GATE(0);
        }
        bf16x8 af[4], bfr[4];
        #pragma unroll
        for (int i = 0; i < 4; ++i)
            af[i] = *(const bf16x8*)(sm + bo + (wm * 64 + i * 16 + lc) * 32 + koff);
        #pragma unroll
        for (int j = 0; j < 4; ++j)
            bfr[j] = *(const bf16x8*)(sm + bo + 4096 + (wn * 64 + j * 16 + lc) * 32 + koff);
        __builtin_amdgcn_s_barrier();   // WAR: reads of bo done before next overwrite
        __builtin_amdgcn_s_setprio(1);
        #pragma unroll
        for (int i = 0; i < 4; ++i)
            #pragma unroll
            for (int j = 0; j < 4; ++j)
                acc[i][j] = __builtin_amdgcn_mfma_f32_16x16x32_bf16(af[i], bfr[j], acc[i][j], 0, 0, 0);
        __builtin_amdgcn_s_setprio(0);
        bo = nb;
    }
}

// ---------------- fused router GEMM: h = xh*wTh + xh*wTl + xl*wTh -----------
// One kernel replaces the 3 z-split GEMMs: stage 4 operand tiles per K-step,
// 3 MFMA products into ONE fp32 acc (same precision as prior hp0+hp1+hp2 sum).
// LDS 64 KiB dbuf; grid (H_R/128=4, N_TOK/128=64) = 256 blocks = 1/CU.
// elems: [0,4K) xh [4K,8K) xl [8K,12K) wh [12K,16K) wl; +16K for buf 1.

__global__ __launch_bounds__(256, 2) void router_gemm_fused(
    const bf16* __restrict__ xh, const bf16* __restrict__ xl,
    const bf16* __restrict__ wTh, const bf16* __restrict__ wTl,
    float* __restrict__ hp) {
    __shared__ bf16 smem[32768];
    const int tid = threadIdx.x;
    const int mbase = blockIdx.y * 128, nbase = blockIdx.x * 128;
    const int c0 = tid, c1 = tid + 256;
    const size_t ra0 = (size_t)(mbase + (c0 >> 2)) * D_MODEL + swz_src_q(c0) * 8;
    const size_t ra1 = (size_t)(mbase + (c1 >> 2)) * D_MODEL + swz_src_q(c1) * 8;
    const size_t rb0 = (size_t)(nbase + (c0 >> 2)) * D_MODEL + swz_src_q(c0) * 8;
    const size_t rb1 = (size_t)(nbase + (c1 >> 2)) * D_MODEL + swz_src_q(c1) * 8;
    const bf16 *pxh0 = xh + ra0, *pxh1 = xh + ra1;
    const bf16 *pxl0 = xl + ra0, *pxl1 = xl + ra1;
    const bf16 *pwh0 = wTh + rb0, *pwh1 = wTh + rb1;
    const bf16 *pwl0 = wTl + rb0, *pwl1 = wTl + rb1;
    const int w = tid >> 6, lane = tid & 63;
    const int wm = w & 1, wn = w >> 1, lc = lane & 15;
    const int koff = ((((lane >> 4) + (lc >> 1)) & 3) * 8);
    const int ws = w * 512;
    f32x4 acc[4][4] = {};
    // prologue: stage K-tile 0 into buf 0
    gload16(pxh0, smem + ws);
    gload16(pxh1, smem + 2048 + ws);
    gload16(pxl0, smem + 4096 + ws);
    gload16(pxl1, smem + 6144 + ws);
    gload16(pwh0, smem + 8192 + ws);
    gload16(pwh1, smem + 10240 + ws);
    gload16(pwl0, smem + 12288 + ws);
    gload16(pwl1, smem + 14336 + ws);
    int bo = 0;
    for (int t = 0; t < D_MODEL / 32; ++t) {
        const int nb = bo ^ 16384;
        if (t + 1 < D_MODEL / 32) {
            const int kb = (t + 1) << 5;
            gload16(pxh0 + kb, smem + nb + ws);
            gload16(pxh1 + kb, smem + nb + 2048 + ws);
            gload16(pxl0 + kb, smem + nb + 4096 + ws);
            gload16(pxl1 + kb, smem + nb + 6144 + ws);
            gload16(pwh0 + kb, smem + nb + 8192 + ws);
            gload16(pwh1 + kb, smem + nb + 10240 + ws);
            gload16(pwl0 + kb, smem + nb + 12288 + ws);
            gload16(pwl1 + kb, smem + nb + 14336 + ws);
            GATE(8);
        } else {
            GATE(0);
        }
        bf16x8 ah[4], al[4], bh[4], bl[4];
        #pragma unroll
        for (int i = 0; i < 4; ++i) {
            const int ro = (wm * 64 + i * 16 + lc) * 32 + koff;
            ah[i] = *(const bf16x8*)(smem + bo + ro);
            al[i] = *(const bf16x8*)(smem + bo + 4096 + ro);
        }
        #pragma unroll
        for (int j = 0; j < 4; ++j) {
            const int ro = (wn * 64 + j * 16 + lc) * 32 + koff;
            bh[j] = *(const bf16x8*)(smem + bo + 8192 + ro);
            bl[j] = *(const bf16x8*)(smem + bo + 12288 + ro);
        }
        __builtin_amdgcn_s_barrier();
        __builtin_amdgcn_s_setprio(1);
        #pragma unroll
        for (int i = 0; i < 4; ++i)
            #pragma unroll
            for (int j = 0; j < 4; ++j) {
                acc[i][j] = __builtin_amdgcn_mfma_f32_16x16x32_bf16(ah[i], bh[j], acc[i][j], 0, 0, 0);
                acc[i][j] = __builtin_amdgcn_mfma_f32_16x16x32_bf16(ah[i], bl[j], acc[i][j], 0, 0, 0);
                acc[i][j] = __builtin_amdgcn_mfma_f32_16x16x32_bf16(al[i], bh[j], acc[i][j], 0, 0, 0);
            }
        __builtin_amdgcn_s_setprio(0);
        bo = nb;
    }
    const int quad = lane >> 4;
    #pragma unroll
    for (int i = 0; i < 4; ++i)
        #pragma unroll
        for (int j = 0; j < 4; ++j) {
            int col = nbase + wn * 64 + j * 16 + lc;
            #pragma unroll
            for (int r = 0; r < 4; ++r) {
                int row = mbase + wm * 64 + i * 16 + quad * 4 + r;
                hp[(size_t)row * H_R + col] = acc[i][j][r];
            }
        }
}

// ---------------- fused LayerNorm + GELU + logits + top-2 -------------------

__global__ __launch_bounds__(256) void ln_router2(
    const float* __restrict__ hp, const float* __restrict__ r1b,
    const float* __restrict__ g, const float* __restrict__ bta,
    const float* __restrict__ r2w, const float* __restrict__ r2b,
    const float* __restrict__ temp, const float* __restrict__ rbias,
    int* __restrict__ top_i, float* __restrict__ top_p,
    int* __restrict__ flaglist, int* __restrict__ meta) {
    __shared__ float Wl[H_R * N_EXP];
    int tid = threadIdx.x;
    for (int i = tid; i < H_R * N_EXP; i += 256) Wl[i] = r2w[i];
    __syncthreads();
    int w = tid >> 6, lane = tid & 63;
    int t = blockIdx.x * 4 + w;
    size_t rbase = (size_t)t * H_R;
    int k0 = lane * 8;
    float v[8];
    {
        f32x4 a0 = *(const f32x4*)(hp + rbase + k0);
        f32x4 a1 = *(const f32x4*)(hp + rbase + k0 + 4);
        f32x4 d0 = *(const f32x4*)(r1b + k0);
        f32x4 d1 = *(const f32x4*)(r1b + k0 + 4);
        #pragma unroll
        for (int k = 0; k < 4; ++k) {
            v[k]     = a0[k] + d0[k];
            v[k + 4] = a1[k] + d1[k];
        }
    }
    float s = 0.f;
    #pragma unroll
    for (int k = 0; k < 8; ++k) s += v[k];
    #pragma unroll
    for (int off = 32; off; off >>= 1) s += __shfl_xor(s, off);
    float mu = s * (1.0f / H_R);
    float q = 0.f;
    #pragma unroll
    for (int k = 0; k < 8; ++k) { float d = v[k] - mu; q += d * d; }
    #pragma unroll
    for (int off = 32; off; off >>= 1) q += __shfl_xor(q, off);
    float scl = 1.0f / sqrtf(q * (1.0f / H_R) + 1e-5f);
    f32x4 g0 = *(const f32x4*)(g + k0), g1 = *(const f32x4*)(g + k0 + 4);
    f32x4 b0 = *(const f32x4*)(bta + k0), b1v = *(const f32x4*)(bta + k0 + 4);
    float G[8] = {g0[0], g0[1], g0[2], g0[3], g1[0], g1[1], g1[2], g1[3]};
    float B[8] = {b0[0], b0[1], b0[2], b0[3], b1v[0], b1v[1], b1v[2], b1v[3]};
    float acc[N_EXP] = {};
    #pragma unroll
    for (int k = 0; k < 8; ++k) {
        float y = gelu_f((v[k] - mu) * scl * G[k] + B[k]);
        const float* wr = &Wl[(k0 + k) * N_EXP];
        #pragma unroll
        for (int e = 0; e < N_EXP; ++e) acc[e] += y * wr[e];
    }
    #pragma unroll
    for (int e = 0; e < N_EXP; ++e)
        #pragma unroll
        for (int off = 32; off; off >>= 1) acc[e] += __shfl_xor(acc[e], off);
    if (lane == 0) {
        float tinv = 1.0f / temp[0];
        float lg[N_EXP];
        #pragma unroll
        for (int e = 0; e < N_EXP; ++e) lg[e] = (acc[e] + r2b[e]) * tinv + rbias[e];
        float v1 = -1e30f; int i1 = 0;
        #pragma unroll
        for (int e = 0; e < N_EXP; ++e) if (lg[e] > v1) { v1 = lg[e]; i1 = e; }
        float v2 = -1e30f; int i2 = 0;
        #pragma unroll
        for (int e = 0; e < N_EXP; ++e) if (e != i1 && lg[e] > v2) { v2 = lg[e]; i2 = e; }
        float v3 = -1e30f;
        #pragma unroll
        for (int e = 0; e < N_EXP; ++e) if (e != i1 && e != i2 && lg[e] > v3) v3 = lg[e];
        float ssum = 0.f;
        #pragma unroll
        for (int e = 0; e < N_EXP; ++e) ssum += __expf(lg[e] - v1);
        float inv = 1.0f / ssum;
        top_i[2 * t] = i1; top_i[2 * t + 1] = i2;
        top_p[2 * t] = inv;
        top_p[2 * t + 1] = __expf(v2 - v1) * inv;
        if (v2 - v3 < 1e-3f) {
            int ix = atomicAdd(&meta[24], 1);
            if (ix < FLAG_CAP) flaglist[ix] = t;
        }
    }
}

// ---------------- fp64 exact rescue for near-tie tokens ---------------------

__global__ __launch_bounds__(256) void router_rescue(
    const float* __restrict__ x, const float* __restrict__ r1w,
    const float* __restrict__ r1b, const float* __restrict__ lng,
    const float* __restrict__ lnb, const float* __restrict__ r2w,
    const float* __restrict__ r2b, const float* __restrict__ temp,
    const float* __restrict__ rbias, const int* __restrict__ flaglist,
    const int* __restrict__ meta, int* __restrict__ top_i, float* __restrict__ top_p) {
    int n = meta[24]; if (n > FLAG_CAP) n = FLAG_CAP;
    if ((int)blockIdx.x >= n) return;
    int t = flaglist[blockIdx.x];
    __shared__ double xs[D_MODEL];
    __shared__ double hbuf[H_R];
    __shared__ double red[8];
    int tid = threadIdx.x;
    for (int k = tid; k < D_MODEL; k += 256) xs[k] = (double)x[(size_t)t * D_MODEL + k];
    __syncthreads();
    for (int c = tid; c < H_R; c += 256) {
        double s = 0.0;
        for (int k = 0; k < D_MODEL; ++k) s += xs[k] * (double)r1w[(size_t)k * H_R + c];
        hbuf[c] = s + (double)r1b[c];
    }
    __syncthreads();
    double ls = 0.0;
    for (int c = tid; c < H_R; c += 256) ls += hbuf[c];
    #pragma unroll
    for (int off = 32; off; off >>= 1) ls += __shfl_xor(ls, off);
    if ((tid & 63) == 0) red[tid >> 6] = ls;
    __syncthreads();
    double mu = (red[0] + red[1] + red[2] + red[3]) * (1.0 / H_R);
    __syncthreads();
    double q = 0.0;
    for (int c = tid; c < H_R; c += 256) { double d = hbuf[c] - mu; q += d * d; }
    #pragma unroll
    for (int off = 32; off; off >>= 1) q += __shfl_xor(q, off);
    if ((tid & 63) == 0) red[tid >> 6] = q;
    __syncthreads();
    double var = (red[0] + red[1] + red[2] + red[3]) * (1.0 / H_R);
    double scl = 1.0 / sqrt(var + 1e-5);
    __syncthreads();
    for (int c = tid; c < H_R; c += 256) {
        double y = (hbuf[c] - mu) * scl * (double)lng[c] + (double)lnb[c];
        hbuf[c] = 0.5 * y * (1.0 + erf(y * 0.70710678118654752440));
    }
    __syncthreads();
    if (tid < N_EXP) {
        double s = 0.0;
        for (int k = 0; k < H_R; ++k) s += hbuf[k] * (double)r2w[k * N_EXP + tid];
        red[tid] = (s + (double)r2b[tid]) / (double)temp[0] + (double)rbias[tid];
    }
    __syncthreads();
    if (tid == 0) {
        double lg[N_EXP];
        #pragma unroll
        for (int e = 0; e < N_EXP; ++e) lg[e] = red[e];
        double v1 = -1e300; int i1 = 0;
        for (int e = 0; e < N_EXP; ++e) if (lg[e] > v1) { v1 = lg[e]; i1 = e; }
        double v2 = -1e300; int i2 = 0;
        for (int e = 0; e < N_EXP; ++e) if (e != i1 && lg[e] > v2) { v2 = lg[e]; i2 = e; }
        double s = 0.0;
        for (int e = 0; e < N_EXP; ++e) s += exp(lg[e] - v1);
        double inv = 1.0 / s;
        top_i[2 * t] = i1; top_i[2 * t + 1] = i2;
        top_p[2 * t] = (float)inv;
        top_p[2 * t + 1] = (float)(exp(v2 - v1) * inv);
    }
}

// ---------------- route_pack: count + scan + scatter, zero global atomics ---

#define RP_T 1024
#define RP_TOK (N_TOK / RP_T)   // 8 tokens per thread

__global__ __launch_bounds__(1024) void route_pack(
    const int* __restrict__ top_i, int* __restrict__ meta,
    int* __restrict__ atok, int* __restrict__ ainv) {
    __shared__ int S[N_EXP][RP_T];
    __shared__ int segbase[N_EXP + 1];
    int tid = threadIdx.x;
    int e_loc[2 * RP_TOK];
    int cnt[N_EXP];
    #pragma unroll
    for (int e = 0; e < N_EXP; ++e) cnt[e] = 0;
    int t0 = tid * RP_TOK;
    #pragma unroll
    for (int q = 0; q < (2 * RP_TOK) / 4; ++q) {
        i32x4 v = *(const i32x4*)(top_i + 2 * t0 + q * 4);
        #pragma unroll
        for (int k = 0; k < 4; ++k) {
            int e = v[k];
            e_loc[q * 4 + k] = e;
            #pragma unroll
            for (int ee = 0; ee < N_EXP; ++ee) if (e == ee) cnt[ee]++;
        }
    }
    #pragma unroll
    for (int e = 0; e < N_EXP; ++e) S[e][tid] = cnt[e];
    __syncthreads();
    for (int off = 1; off < RP_T; off <<= 1) {
        int tmp[N_EXP];
        #pragma unroll
        for (int e = 0; e < N_EXP; ++e)
            tmp[e] = (tid >= off) ? S[e][tid - off] : 0;
        __syncthreads();
        #pragma unroll
        for (int e = 0; e < N_EXP; ++e) S[e][tid] += tmp[e];
        __syncthreads();
    }
    if (tid == 0) {
        int o = 0;
        #pragma unroll
        for (int e = 0; e < N_EXP; ++e) {
            segbase[e] = o;
            int tot = S[e][RP_T - 1];
            meta[e] = tot;
            meta[8 + e] = o;
            o += tot;
        }
        segbase[N_EXP] = o;
    }
    __syncthreads();
    int pos[N_EXP];
    #pragma unroll
    for (int e = 0; e < N_EXP; ++e)
        pos[e] = segbase[e] + S[e][tid] - cnt[e];
    #pragma unroll
    for (int k = 0; k < 2 * RP_TOK; ++k) {
        int e = e_loc[k];
        int a = 0;
        #pragma unroll
        for (int ee = 0; ee < N_EXP; ++ee) if (e == ee) a = pos[ee]++;
        atok[a] = t0 + (k >> 1);
        ainv[2 * t0 + k] = a;
    }
}

// ---------------- expert GEMMs: 128x128 BK=32 dbuf, 4 blocks/CU -------------

__global__ __launch_bounds__(256, 4) void expert_gemm1(
    const bf16* __restrict__ xb, const bf16* __restrict__ W1T,
    const float* __restrict__ b1, const int* __restrict__ meta,
    const int* __restrict__ atok, bf16* __restrict__ act) {
    __shared__ bf16 smem[16384];           // 32 KiB dbuf
    int e = blockIdx.z;
    int rows = meta[e];
    int mloc = blockIdx.y * 128;
    if (mloc >= rows) return;
    int base = meta[8 + e];
    int tid = threadIdx.x;
    int nbase = blockIdx.x * 128;
    int c0 = tid, c1 = tid + 256;
    int r0 = mloc + (c0 >> 2); if (r0 > rows - 1) r0 = rows - 1;
    int r1 = mloc + (c1 >> 2); if (r1 > rows - 1) r1 = rows - 1;
    const bf16* gA0 = xb + (size_t)atok[base + r0] * D_MODEL + swz_src_q(c0) * 8;
    const bf16* gA1 = xb + (size_t)atok[base + r1] * D_MODEL + swz_src_q(c1) * 8;
    const bf16* Bt = W1T + ((size_t)e * F_FF + nbase) * D_MODEL;
    const bf16* gB0 = Bt + (size_t)(c0 >> 2) * D_MODEL + swz_src_q(c0) * 8;
    const bf16* gB1 = Bt + (size_t)(c1 >> 2) * D_MODEL + swz_src_q(c1) * 8;
    f32x4 acc[4][4] = {};
    gemm128_core(gA0, gA1, gB0, gB1, D_MODEL, smem, acc);
    const int lane = tid & 63;
    const int w = tid >> 6;
    const int wm = w & 1, wn = w >> 1;
    const int lc = lane & 15, qd = lane >> 4;
    const bool oddE = (e & 1) != 0;
    #pragma unroll
    for (int i = 0; i < 4; ++i) {
        #pragma unroll
        for (int j = 0; j < 4; ++j) {
            int col = nbase + wn * 64 + j * 16 + lc;
            float bias = b1[e * F_FF + col];
            #pragma unroll
            for (int r = 0; r < 4; ++r) {
                int rloc = mloc + wm * 64 + i * 16 + qd * 4 + r;
                if (rloc < rows) {
                    float vv = acc[i][j][r] + bias;
                    vv = oddE ? silu_f(vv) : gelu_f(vv);
                    act[(size_t)(base + rloc) * F_FF + col] = (bf16)vv;
                }
            }
        }
    }
}

__global__ __launch_bounds__(256, 4) void expert_gemm2(
    const bf16* __restrict__ act, const bf16* __restrict__ W2T,
    const float* __restrict__ b2, const int* __restrict__ meta,
    float* __restrict__ eo) {
    __shared__ bf16 smem[16384];
    int e = blockIdx.z;
    int rows = meta[e];
    int mloc = blockIdx.y * 128;
    if (mloc >= rows) return;
    int base = meta[8 + e];
    int tid = threadIdx.x;
    int nbase = blockIdx.x * 128;
    int c0 = tid, c1 = tid + 256;
    int r0 = mloc + (c0 >> 2); if (r0 > rows - 1) r0 = rows - 1;
    int r1 = mloc + (c1 >> 2); if (r1 > rows - 1) r1 = rows - 1;
    const bf16* gA0 = act + (size_t)(base + r0) * F_FF + swz_src_q(c0) * 8;
    const bf16* gA1 = act + (size_t)(base + r1) * F_FF + swz_src_q(c1) * 8;
    const bf16* Bt = W2T + ((size_t)e * D_MODEL + nbase) * F_FF;
    const bf16* gB0 = Bt + (size_t)(c0 >> 2) * F_FF + swz_src_q(c0) * 8;
    const bf16* gB1 = Bt + (size_t)(c1 >> 2) * F_FF + swz_src_q(c1) * 8;
    f32x4 acc[4][4] = {};
    gemm128_core(gA0, gA1, gB0, gB1, F_FF, smem, acc);
    const int lane = tid & 63;
    const int w = tid >> 6;
    const int wm = w & 1, wn = w >> 1;
    const int lc = lane & 15, qd = lane >> 4;
    #pragma unroll
    for (int i = 0; i < 4; ++i) {
        #pragma unroll
        for (int j = 0; j < 4; ++j) {
            int col = nbase + wn * 64 + j * 16 + lc;
            float bias = b2[e * D_MODEL + col];
            #pragma unroll
            for (int r = 0; r < 4; ++r) {
                int rloc = mloc + wm * 64 + i * 16 + qd * 4 + r;
                if (rloc < rows)
                    eo[(size_t)(base + rloc) * D_MODEL + col] = acc[i][j][r] + bias;
            }
        }
    }
}

// ---------------- weighted combine ------------------------------------------

__global__ __launch_bounds__(256) void combine_kernel(
    const float* __restrict__ eo, const int* __restrict__ ainv,
    const float* __restrict__ top_p, float* __restrict__ out) {
    int t = blockIdx.x;
    int s0 = ainv[2 * t], s1 = ainv[2 * t + 1];
    float p0 = top_p[2 * t], p1 = top_p[2 * t + 1];
    int c = threadIdx.x * 4;
    f32x4 a = *(const f32x4*)(eo + (size_t)s0 * D_MODEL + c);
    f32x4 b = *(const f32x4*)(eo + (size_t)s1 * D_MODEL + c);
    f32x4 o;
    #pragma unroll
    for (int k = 0; k < 4; ++k) o[k] = a[k] * p0 + b[k] * p1;
    *(f32x4*)(out + (size_t)t * D_MODEL + c) = o;
}

// ---------------- launch ----------------------------------------------------

extern "C" void kernel_launch(void* const* d_in, const int* in_sizes, int n_in,
                              void* d_out, int out_size, void* d_ws, size_t ws_size,
                              hipStream_t stream) {
    const float* x     = (const float*)d_in[0];
    const float* r1w   = (const float*)d_in[1];
    const float* r1b   = (const float*)d_in[2];
    const float* lng   = (const float*)d_in[3];
    const float* lnb   = (const float*)d_in[4];
    const float* r2w   = (const float*)d_in[5];
    const float* r2b   = (const float*)d_in[6];
    const float* temp  = (const float*)d_in[7];
    const float* rbias = (const float*)d_in[8];
    const float* W1    = (const float*)d_in[9];
    const float* b1    = (const float*)d_in[10];
    const float* W2    = (const float*)d_in[11];
    const float* b2    = (const float*)d_in[12];
    float* out = (float*)d_out;

    char* ws = (char*)d_ws;
    size_t off = 0;
    auto alloc = [&](size_t bytes) -> void* {
        void* p = ws + off;
        off = (off + bytes + 255) & ~(size_t)255;
        return p;
    };
    bf16*  xh    = (bf16*)alloc((size_t)N_TOK * D_MODEL * 2);
    bf16*  xl    = (bf16*)alloc((size_t)N_TOK * D_MODEL * 2);
    bf16*  r1wTh = (bf16*)alloc((size_t)H_R * D_MODEL * 2);
    bf16*  r1wTl = (bf16*)alloc((size_t)H_R * D_MODEL * 2);
    bf16*  W1T   = (bf16*)alloc((size_t)N_EXP * F_FF * D_MODEL * 2);
    bf16*  W2T   = (bf16*)alloc((size_t)N_EXP * D_MODEL * F_FF * 2);
    float* hp    = (float*)alloc((size_t)N_TOK * H_R * 4);
    int*   top_i = (int*)alloc((size_t)N_TOK * 2 * 4);
    float* top_p = (float*)alloc((size_t)N_TOK * 2 * 4);
    int*   meta  = (int*)alloc(256);
    int*   flags = (int*)alloc(FLAG_CAP * 4);
    int*   atok  = (int*)alloc((size_t)2 * N_TOK * 4);
    int*   ainv  = (int*)alloc((size_t)2 * N_TOK * 4);
    bf16*  actb  = (bf16*)alloc((size_t)2 * N_TOK * F_FF * 2);
    float* eo    = (float*)alloc((size_t)2 * N_TOK * D_MODEL * 4);
    (void)ws_size; (void)n_in; (void)in_sizes;

    hipMemsetAsync(meta, 0, 256, stream);

    convert_x_split<<<(N_TOK * D_MODEL) / (256 * 8), 256, 0, stream>>>(x, xh, xl);
    transpose_split<<<dim3(H_R / 32, D_MODEL / 32, 1), 256, 0, stream>>>(
        r1w, r1wTh, r1wTl, D_MODEL, H_R);

    router_gemm_fused<<<dim3(H_R / 128, N_TOK / 128, 1), 256, 0, stream>>>(
        xh, xl, r1wTh, r1wTl, hp);
    ln_router2<<<N_TOK / 4, 256, 0, stream>>>(
        hp, r1b, lng, lnb, r2w, r2b, temp, rbias, top_i, top_p, flags, meta);
    router_rescue<<<FLAG_CAP, 256, 0, stream>>>(
        x, r1w, r1b, lng, lnb, r2w, r2b, temp, rbias, flags, meta, top_i, top_p);
    route_pack<<<1, RP_T, 0, stream>>>(top_i, meta, atok, ainv);

    // weight transposes placed just before their consumers (L2/L3-warm)
    transpose_bf16_64<<<dim3(F_FF / 64, D_MODEL / 64, N_EXP), 256, 0, stream>>>(
        W1, W1T, D_MODEL, F_FF);
    transpose_bf16_64<<<dim3(D_MODEL / 64, F_FF / 64, N_EXP), 256, 0, stream>>>(
        W2, W2T, F_FF, D_MODEL);

    expert_gemm1<<<dim3(F_FF / 128, N_TOK / 128, N_EXP), 256, 0, stream>>>(
        xh, W1T, b1, meta, atok, actb);
    expert_gemm2<<<dim3(D_MODEL / 128, N_TOK / 128, N_EXP), 256, 0, stream>>>(
        actb, W2T, b2, meta, eo);
    combine_kernel<<<N_TOK, 256, 0, stream>>>(eo, ainv, top_p, out);
}

// Round 6
// 524.095 us; speedup vs baseline: 1.2474x; 1.0253x over previous
//
#include <hip/hip_runtime.h>
#include <hip/hip_bf16.h>
#include <stdint.h>

typedef __bf16 bf16;
typedef bf16 bf16x8 __attribute__((ext_vector_type(8)));
typedef bf16 bf16x4 __attribute__((ext_vector_type(4)));
typedef float f32x4 __attribute__((ext_vector_type(4)));
typedef int i32x4 __attribute__((ext_vector_type(4)));

#define N_TOK 8192
#define D_MODEL 1024
#define H_R 512
#define N_EXP 6
#define F_FF 1536
#define FLAG_CAP 1024

// Abramowitz-Stegun 7.1.26: |err| <= 1.5e-7
__device__ __forceinline__ float erf_fast(float x) {
    float ax = fabsf(x);
    float t = 1.0f / (1.0f + 0.3275911f * ax);
    float p = t * (0.254829592f + t * (-0.284496736f + t * (1.421413741f +
              t * (-1.453152027f + t * 1.061405429f))));
    float r = 1.0f - p * __expf(-ax * ax);
    return copysignf(r, x);
}
__device__ __forceinline__ float gelu_f(float x) {
    return 0.5f * x * (1.0f + erf_fast(x * 0.70710678118654752f));
}
__device__ __forceinline__ float silu_f(float x) {
    return x * (1.0f / (1.0f + __expf(-x)));
}

typedef __attribute__((address_space(1))) const void* gas1;
typedef __attribute__((address_space(3))) void* las3;

__device__ __forceinline__ void gload16(const void* g, void* l) {
    __builtin_amdgcn_global_load_lds((gas1)g, (las3)l, 16, 0, 0);
}

// LDS chunk swizzle (verified): row r's logical 16B chunk q lives at
// chunk-slot (q + (r>>1)) & 3. Source-side inverse:
__device__ __forceinline__ int swz_src_q(int c) {
    return (((c & 3) - ((c >> 2) >> 1)) & 3);
}

// counted waitcnt + barrier release point; "memory" clobber pins ds_reads below
#define GATE(N) asm volatile("s_waitcnt vmcnt(" #N ")\n\ts_barrier" ::: "memory")

// ---------------- conversion / transpose ------------------------------------

__global__ __launch_bounds__(256) void convert_x_split(
    const float* __restrict__ x, bf16* __restrict__ xh, bf16* __restrict__ xl) {
    size_t i = ((size_t)blockIdx.x * 256 + threadIdx.x) * 8;
    f32x4 a = *(const f32x4*)(x + i);
    f32x4 b = *(const f32x4*)(x + i + 4);
    float v[8] = {a[0], a[1], a[2], a[3], b[0], b[1], b[2], b[3]};
    bf16x8 vh, vl;
    #pragma unroll
    for (int k = 0; k < 8; ++k) {
        bf16 h = (bf16)v[k];
        vh[k] = h;
        vl[k] = (bf16)(v[k] - (float)h);
    }
    *(bf16x8*)(xh + i) = vh;
    *(bf16x8*)(xl + i) = vl;
}

__global__ __launch_bounds__(256) void transpose_bf16_64(
    const float* __restrict__ in, bf16* __restrict__ out, int R, int C) {
    __shared__ float tile[64][65];
    const float* inp = in + (size_t)blockIdx.z * R * C;
    bf16* op = out + (size_t)blockIdx.z * R * C;
    int tx = threadIdx.x & 15, ty = threadIdx.x >> 4;
    int r0 = blockIdx.y * 64, c0 = blockIdx.x * 64;
    #pragma unroll
    for (int p = 0; p < 4; ++p) {
        int row = p * 16 + ty;
        f32x4 v = *(const f32x4*)(inp + (size_t)(r0 + row) * C + c0 + tx * 4);
        tile[row][tx * 4 + 0] = v[0];
        tile[row][tx * 4 + 1] = v[1];
        tile[row][tx * 4 + 2] = v[2];
        tile[row][tx * 4 + 3] = v[3];
    }
    __syncthreads();
    #pragma unroll
    for (int p = 0; p < 4; ++p) {
        int cc = p * 16 + ty;
        bf16x4 o;
        #pragma unroll
        for (int k = 0; k < 4; ++k) o[k] = (bf16)tile[tx * 4 + k][cc];
        *(bf16x4*)(op + (size_t)(c0 + cc) * R + r0 + tx * 4) = o;
    }
}

__global__ __launch_bounds__(256) void transpose_split(
    const float* __restrict__ in, bf16* __restrict__ oh, bf16* __restrict__ ol,
    int R, int C) {
    __shared__ float tile[32][33];
    int tx = threadIdx.x & 31, ty = threadIdx.x >> 5;
    int r0 = blockIdx.y * 32, c0 = blockIdx.x * 32;
    #pragma unroll
    for (int yy = ty; yy < 32; yy += 8)
        tile[yy][tx] = in[(size_t)(r0 + yy) * C + c0 + tx];
    __syncthreads();
    #pragma unroll
    for (int yy = ty; yy < 32; yy += 8) {
        float v = tile[tx][yy];
        bf16 h = (bf16)v;
        size_t o = (size_t)(c0 + yy) * R + r0 + tx;
        oh[o] = h;
        ol[o] = (bf16)(v - (float)h);
    }
}

// ---------------- 128x128 BK=32 triple-buffered core (expert path) ----------
// 256 threads = 4 waves (2M x 2N). LDS 48 KiB (3 bufs) -> 3 blocks/CU.
// Prefetch depth 2: at iter t issue loads for t+2; GATE(8) waits for tile t
// while t+1,t+2 (8 loads/thread) stay in flight -> issue-to-use ~2 K-tiles,
// covering L2/L3 miss latency. Buffer written at iter t (for t+2) is the one
// read at iter t-1 (mod 3) — same one-barrier WAR separation as the verified
// double-buffer pattern.
// Per-buf layout (bf16 elems): A [0,4K) B [4K,8K). Bufs at 0, 8K, 16K.

__device__ __forceinline__ void gemm128_core(
    const bf16* gA0, const bf16* gA1, const bf16* gB0, const bf16* gB1,
    int K, bf16* sm, f32x4 acc[4][4])
{
    const int tid = threadIdx.x;
    const int lane = tid & 63;
    const int w = tid >> 6;
    const int wm = w & 1, wn = w >> 1;
    const int lc = lane & 15;
    const int koff = ((((lane >> 4) + (lc >> 1)) & 3) * 8);
    const int ws = w * 512;
    const int NT = K >> 5;
    // prologue: stage tiles 0,1 into bufs 0,1
    gload16(gA0,      sm + ws);
    gload16(gA1,      sm + 2048 + ws);
    gload16(gB0,      sm + 4096 + ws);
    gload16(gB1,      sm + 6144 + ws);
    gload16(gA0 + 32, sm + 8192 + ws);
    gload16(gA1 + 32, sm + 8192 + 2048 + ws);
    gload16(gB0 + 32, sm + 8192 + 4096 + ws);
    gload16(gB1 + 32, sm + 8192 + 6144 + ws);
    int cur = 0, nxt = 8192, fut = 16384;
    for (int t = 0; t < NT; ++t) {
        if (t + 2 < NT) {
            const int kb = (t + 2) << 5;
            gload16(gA0 + kb, sm + fut + ws);
            gload16(gA1 + kb, sm + fut + 2048 + ws);
            gload16(gB0 + kb, sm + fut + 4096 + ws);
            gload16(gB1 + kb, sm + fut + 6144 + ws);
            GATE(8);          // tile t done; t+1,t+2 (8/thread) in flight
        } else if (t + 1 < NT) {
            GATE(4);
        } else {
            GATE(0);
        }
        bf16x8 af[4], bfr[4];
        #pragma unroll
        for (int i = 0; i < 4; ++i)
            af[i] = *(const bf16x8*)(sm + cur + (wm * 64 + i * 16 + lc) * 32 + koff);
        #pragma unroll
        for (int j = 0; j < 4; ++j)
            bfr[j] = *(const bf16x8*)(sm + cur + 4096 + (wn * 64 + j * 16 + lc) * 32 + koff);
        __builtin_amdgcn_s_barrier();   // WAR: reads of cur issued before next overwrite
        __builtin_amdgcn_s_setprio(1);
        #pragma unroll
        for (int i = 0; i < 4; ++i)
            #pragma unroll
            for (int j = 0; j < 4; ++j)
                acc[i][j] = __builtin_amdgcn_mfma_f32_16x16x32_bf16(af[i], bfr[j], acc[i][j], 0, 0, 0);
        __builtin_amdgcn_s_setprio(0);
        int old = cur; cur = nxt; nxt = fut; fut = old;
    }
}

// ---------------- fused router GEMM: h = xh*wTh + xh*wTl + xl*wTh -----------

__global__ __launch_bounds__(256, 2) void router_gemm_fused(
    const bf16* __restrict__ xh, const bf16* __restrict__ xl,
    const bf16* __restrict__ wTh, const bf16* __restrict__ wTl,
    float* __restrict__ hp) {
    __shared__ bf16 smem[32768];
    const int tid = threadIdx.x;
    const int mbase = blockIdx.y * 128, nbase = blockIdx.x * 128;
    const int c0 = tid, c1 = tid + 256;
    const size_t ra0 = (size_t)(mbase + (c0 >> 2)) * D_MODEL + swz_src_q(c0) * 8;
    const size_t ra1 = (size_t)(mbase + (c1 >> 2)) * D_MODEL + swz_src_q(c1) * 8;
    const size_t rb0 = (size_t)(nbase + (c0 >> 2)) * D_MODEL + swz_src_q(c0) * 8;
    const size_t rb1 = (size_t)(nbase + (c1 >> 2)) * D_MODEL + swz_src_q(c1) * 8;
    const bf16 *pxh0 = xh + ra0, *pxh1 = xh + ra1;
    const bf16 *pxl0 = xl + ra0, *pxl1 = xl + ra1;
    const bf16 *pwh0 = wTh + rb0, *pwh1 = wTh + rb1;
    const bf16 *pwl0 = wTl + rb0, *pwl1 = wTl + rb1;
    const int w = tid >> 6, lane = tid & 63;
    const int wm = w & 1, wn = w >> 1, lc = lane & 15;
    const int koff = ((((lane >> 4) + (lc >> 1)) & 3) * 8);
    const int ws = w * 512;
    f32x4 acc[4][4] = {};
    gload16(pxh0, smem + ws);
    gload16(pxh1, smem + 2048 + ws);
    gload16(pxl0, smem + 4096 + ws);
    gload16(pxl1, smem + 6144 + ws);
    gload16(pwh0, smem + 8192 + ws);
    gload16(pwh1, smem + 10240 + ws);
    gload16(pwl0, smem + 12288 + ws);
    gload16(pwl1, smem + 14336 + ws);
    int bo = 0;
    for (int t = 0; t < D_MODEL / 32; ++t) {
        const int nb = bo ^ 16384;
        if (t + 1 < D_MODEL / 32) {
            const int kb = (t + 1) << 5;
            gload16(pxh0 + kb, smem + nb + ws);
            gload16(pxh1 + kb, smem + nb + 2048 + ws);
            gload16(pxl0 + kb, smem + nb + 4096 + ws);
            gload16(pxl1 + kb, smem + nb + 6144 + ws);
            gload16(pwh0 + kb, smem + nb + 8192 + ws);
            gload16(pwh1 + kb, smem + nb + 10240 + ws);
            gload16(pwl0 + kb, smem + nb + 12288 + ws);
            gload16(pwl1 + kb, smem + nb + 14336 + ws);
            GATE(8);
        } else {
            GATE(0);
        }
        bf16x8 ah[4], al[4], bh[4], bl[4];
        #pragma unroll
        for (int i = 0; i < 4; ++i) {
            const int ro = (wm * 64 + i * 16 + lc) * 32 + koff;
            ah[i] = *(const bf16x8*)(smem + bo + ro);
            al[i] = *(const bf16x8*)(smem + bo + 4096 + ro);
        }
        #pragma unroll
        for (int j = 0; j < 4; ++j) {
            const int ro = (wn * 64 + j * 16 + lc) * 32 + koff;
            bh[j] = *(const bf16x8*)(smem + bo + 8192 + ro);
            bl[j] = *(const bf16x8*)(smem + bo + 12288 + ro);
        }
        __builtin_amdgcn_s_barrier();
        __builtin_amdgcn_s_setprio(1);
        #pragma unroll
        for (int i = 0; i < 4; ++i)
            #pragma unroll
            for (int j = 0; j < 4; ++j) {
                acc[i][j] = __builtin_amdgcn_mfma_f32_16x16x32_bf16(ah[i], bh[j], acc[i][j], 0, 0, 0);
                acc[i][j] = __builtin_amdgcn_mfma_f32_16x16x32_bf16(ah[i], bl[j], acc[i][j], 0, 0, 0);
                acc[i][j] = __builtin_amdgcn_mfma_f32_16x16x32_bf16(al[i], bh[j], acc[i][j], 0, 0, 0);
            }
        __builtin_amdgcn_s_setprio(0);
        bo = nb;
    }
    const int quad = lane >> 4;
    #pragma unroll
    for (int i = 0; i < 4; ++i)
        #pragma unroll
        for (int j = 0; j < 4; ++j) {
            int col = nbase + wn * 64 + j * 16 + lc;
            #pragma unroll
            for (int r = 0; r < 4; ++r) {
                int row = mbase + wm * 64 + i * 16 + quad * 4 + r;
                hp[(size_t)row * H_R + col] = acc[i][j][r];
            }
        }
}

// ---------------- fused LayerNorm + GELU + logits + top-2 -------------------

__global__ __launch_bounds__(256) void ln_router2(
    const float* __restrict__ hp, const float* __restrict__ r1b,
    const float* __restrict__ g, const float* __restrict__ bta,
    const float* __restrict__ r2w, const float* __restrict__ r2b,
    const float* __restrict__ temp, const float* __restrict__ rbias,
    int* __restrict__ top_i, float* __restrict__ top_p,
    int* __restrict__ flaglist, int* __restrict__ meta) {
    __shared__ float Wl[H_R * N_EXP];
    int tid = threadIdx.x;
    for (int i = tid; i < H_R * N_EXP; i += 256) Wl[i] = r2w[i];
    __syncthreads();
    int w = tid >> 6, lane = tid & 63;
    int t = blockIdx.x * 4 + w;
    size_t rbase = (size_t)t * H_R;
    int k0 = lane * 8;
    float v[8];
    {
        f32x4 a0 = *(const f32x4*)(hp + rbase + k0);
        f32x4 a1 = *(const f32x4*)(hp + rbase + k0 + 4);
        f32x4 d0 = *(const f32x4*)(r1b + k0);
        f32x4 d1 = *(const f32x4*)(r1b + k0 + 4);
        #pragma unroll
        for (int k = 0; k < 4; ++k) {
            v[k]     = a0[k] + d0[k];
            v[k + 4] = a1[k] + d1[k];
        }
    }
    float s = 0.f;
    #pragma unroll
    for (int k = 0; k < 8; ++k) s += v[k];
    #pragma unroll
    for (int off = 32; off; off >>= 1) s += __shfl_xor(s, off);
    float mu = s * (1.0f / H_R);
    float q = 0.f;
    #pragma unroll
    for (int k = 0; k < 8; ++k) { float d = v[k] - mu; q += d * d; }
    #pragma unroll
    for (int off = 32; off; off >>= 1) q += __shfl_xor(q, off);
    float scl = 1.0f / sqrtf(q * (1.0f / H_R) + 1e-5f);
    f32x4 g0 = *(const f32x4*)(g + k0), g1 = *(const f32x4*)(g + k0 + 4);
    f32x4 b0 = *(const f32x4*)(bta + k0), b1v = *(const f32x4*)(bta + k0 + 4);
    float G[8] = {g0[0], g0[1], g0[2], g0[3], g1[0], g1[1], g1[2], g1[3]};
    float B[8] = {b0[0], b0[1], b0[2], b0[3], b1v[0], b1v[1], b1v[2], b1v[3]};
    float acc[N_EXP] = {};
    #pragma unroll
    for (int k = 0; k < 8; ++k) {
        float y = gelu_f((v[k] - mu) * scl * G[k] + B[k]);
        const float* wr = &Wl[(k0 + k) * N_EXP];
        #pragma unroll
        for (int e = 0; e < N_EXP; ++e) acc[e] += y * wr[e];
    }
    #pragma unroll
    for (int e = 0; e < N_EXP; ++e)
        #pragma unroll
        for (int off = 32; off; off >>= 1) acc[e] += __shfl_xor(acc[e], off);
    if (lane == 0) {
        float tinv = 1.0f / temp[0];
        float lg[N_EXP];
        #pragma unroll
        for (int e = 0; e < N_EXP; ++e) lg[e] = (acc[e] + r2b[e]) * tinv + rbias[e];
        float v1 = -1e30f; int i1 = 0;
        #pragma unroll
        for (int e = 0; e < N_EXP; ++e) if (lg[e] > v1) { v1 = lg[e]; i1 = e; }
        float v2 = -1e30f; int i2 = 0;
        #pragma unroll
        for (int e = 0; e < N_EXP; ++e) if (e != i1 && lg[e] > v2) { v2 = lg[e]; i2 = e; }
        float v3 = -1e30f;
        #pragma unroll
        for (int e = 0; e < N_EXP; ++e) if (e != i1 && e != i2 && lg[e] > v3) v3 = lg[e];
        float ssum = 0.f;
        #pragma unroll
        for (int e = 0; e < N_EXP; ++e) ssum += __expf(lg[e] - v1);
        float inv = 1.0f / ssum;
        top_i[2 * t] = i1; top_i[2 * t + 1] = i2;
        top_p[2 * t] = inv;
        top_p[2 * t + 1] = __expf(v2 - v1) * inv;
        if (v2 - v3 < 1e-3f) {
            int ix = atomicAdd(&meta[24], 1);
            if (ix < FLAG_CAP) flaglist[ix] = t;
        }
    }
}

// ---------------- fp64 exact rescue for near-tie tokens ---------------------

__global__ __launch_bounds__(256) void router_rescue(
    const float* __restrict__ x, const float* __restrict__ r1w,
    const float* __restrict__ r1b, const float* __restrict__ lng,
    const float* __restrict__ lnb, const float* __restrict__ r2w,
    const float* __restrict__ r2b, const float* __restrict__ temp,
    const float* __restrict__ rbias, const int* __restrict__ flaglist,
    const int* __restrict__ meta, int* __restrict__ top_i, float* __restrict__ top_p) {
    int n = meta[24]; if (n > FLAG_CAP) n = FLAG_CAP;
    if ((int)blockIdx.x >= n) return;
    int t = flaglist[blockIdx.x];
    __shared__ double xs[D_MODEL];
    __shared__ double hbuf[H_R];
    __shared__ double red[8];
    int tid = threadIdx.x;
    for (int k = tid; k < D_MODEL; k += 256) xs[k] = (double)x[(size_t)t * D_MODEL + k];
    __syncthreads();
    for (int c = tid; c < H_R; c += 256) {
        double s = 0.0;
        for (int k = 0; k < D_MODEL; ++k) s += xs[k] * (double)r1w[(size_t)k * H_R + c];
        hbuf[c] = s + (double)r1b[c];
    }
    __syncthreads();
    double ls = 0.0;
    for (int c = tid; c < H_R; c += 256) ls += hbuf[c];
    #pragma unroll
    for (int off = 32; off; off >>= 1) ls += __shfl_xor(ls, off);
    if ((tid & 63) == 0) red[tid >> 6] = ls;
    __syncthreads();
    double mu = (red[0] + red[1] + red[2] + red[3]) * (1.0 / H_R);
    __syncthreads();
    double q = 0.0;
    for (int c = tid; c < H_R; c += 256) { double d = hbuf[c] - mu; q += d * d; }
    #pragma unroll
    for (int off = 32; off; off >>= 1) q += __shfl_xor(q, off);
    if ((tid & 63) == 0) red[tid >> 6] = q;
    __syncthreads();
    double var = (red[0] + red[1] + red[2] + red[3]) * (1.0 / H_R);
    double scl = 1.0 / sqrt(var + 1e-5);
    __syncthreads();
    for (int c = tid; c < H_R; c += 256) {
        double y = (hbuf[c] - mu) * scl * (double)lng[c] + (double)lnb[c];
        hbuf[c] = 0.5 * y * (1.0 + erf(y * 0.70710678118654752440));
    }
    __syncthreads();
    if (tid < N_EXP) {
        double s = 0.0;
        for (int k = 0; k < H_R; ++k) s += hbuf[k] * (double)r2w[k * N_EXP + tid];
        red[tid] = (s + (double)r2b[tid]) / (double)temp[0] + (double)rbias[tid];
    }
    __syncthreads();
    if (tid == 0) {
        double lg[N_EXP];
        #pragma unroll
        for (int e = 0; e < N_EXP; ++e) lg[e] = red[e];
        double v1 = -1e300; int i1 = 0;
        for (int e = 0; e < N_EXP; ++e) if (lg[e] > v1) { v1 = lg[e]; i1 = e; }
        double v2 = -1e300; int i2 = 0;
        for (int e = 0; e < N_EXP; ++e) if (e != i1 && lg[e] > v2) { v2 = lg[e]; i2 = e; }
        double s = 0.0;
        for (int e = 0; e < N_EXP; ++e) s += exp(lg[e] - v1);
        double inv = 1.0 / s;
        top_i[2 * t] = i1; top_i[2 * t + 1] = i2;
        top_p[2 * t] = (float)inv;
        top_p[2 * t + 1] = (float)(exp(v2 - v1) * inv);
    }
}

// ---------------- route_pack: count + scan + scatter, zero global atomics ---

#define RP_T 1024
#define RP_TOK (N_TOK / RP_T)   // 8 tokens per thread

__global__ __launch_bounds__(1024) void route_pack(
    const int* __restrict__ top_i, int* __restrict__ meta,
    int* __restrict__ atok, int* __restrict__ ainv) {
    __shared__ int S[N_EXP][RP_T];
    __shared__ int segbase[N_EXP + 1];
    int tid = threadIdx.x;
    int e_loc[2 * RP_TOK];
    int cnt[N_EXP];
    #pragma unroll
    for (int e = 0; e < N_EXP; ++e) cnt[e] = 0;
    int t0 = tid * RP_TOK;
    #pragma unroll
    for (int q = 0; q < (2 * RP_TOK) / 4; ++q) {
        i32x4 v = *(const i32x4*)(top_i + 2 * t0 + q * 4);
        #pragma unroll
        for (int k = 0; k < 4; ++k) {
            int e = v[k];
            e_loc[q * 4 + k] = e;
            #pragma unroll
            for (int ee = 0; ee < N_EXP; ++ee) if (e == ee) cnt[ee]++;
        }
    }
    #pragma unroll
    for (int e = 0; e < N_EXP; ++e) S[e][tid] = cnt[e];
    __syncthreads();
    for (int off = 1; off < RP_T; off <<= 1) {
        int tmp[N_EXP];
        #pragma unroll
        for (int e = 0; e < N_EXP; ++e)
            tmp[e] = (tid >= off) ? S[e][tid - off] : 0;
        __syncthreads();
        #pragma unroll
        for (int e = 0; e < N_EXP; ++e) S[e][tid] += tmp[e];
        __syncthreads();
    }
    if (tid == 0) {
        int o = 0;
        #pragma unroll
        for (int e = 0; e < N_EXP; ++e) {
            segbase[e] = o;
            int tot = S[e][RP_T - 1];
            meta[e] = tot;
            meta[8 + e] = o;
            o += tot;
        }
        segbase[N_EXP] = o;
    }
    __syncthreads();
    int pos[N_EXP];
    #pragma unroll
    for (int e = 0; e < N_EXP; ++e)
        pos[e] = segbase[e] + S[e][tid] - cnt[e];
    #pragma unroll
    for (int k = 0; k < 2 * RP_TOK; ++k) {
        int e = e_loc[k];
        int a = 0;
        #pragma unroll
        for (int ee = 0; ee < N_EXP; ++ee) if (e == ee) a = pos[ee]++;
        atok[a] = t0 + (k >> 1);
        ainv[2 * t0 + k] = a;
    }
}

// ---------------- expert GEMMs: XCD-grouped 1D grid, PD2 pipeline -----------
// Decode so all NX x-siblings (sharing one A-panel) land on the SAME XCD with
// adjacent dispatch slots: id = xcd + 8*(gl*NX + x), group g = gl*8 + xcd.
// g = y*6 + e interleaving spreads active groups uniformly over XCDs.

#define NX1 (F_FF / 128)     // 12
#define NX2 (D_MODEL / 128)  // 8

__global__ __launch_bounds__(256, 3) void expert_gemm1(
    const bf16* __restrict__ xb, const bf16* __restrict__ W1T,
    const float* __restrict__ b1, const int* __restrict__ meta,
    const int* __restrict__ atok, bf16* __restrict__ act) {
    __shared__ bf16 smem[24576];           // 48 KiB: 3 bufs x (A 4K | B 4K)
    const int id = blockIdx.x;
    const int xcd = id & 7, slot = id >> 3;
    const int xt = slot % NX1;
    const int g = (slot / NX1) * 8 + xcd;  // [0, 384)
    const int e = g % N_EXP, y = g / N_EXP;
    int rows = meta[e];
    int mloc = y * 128;
    if (mloc >= rows) return;
    int base = meta[8 + e];
    int tid = threadIdx.x;
    int nbase = xt * 128;
    int c0 = tid, c1 = tid + 256;
    int r0 = mloc + (c0 >> 2); if (r0 > rows - 1) r0 = rows - 1;
    int r1 = mloc + (c1 >> 2); if (r1 > rows - 1) r1 = rows - 1;
    const bf16* gA0 = xb + (size_t)atok[base + r0] * D_MODEL + swz_src_q(c0) * 8;
    const bf16* gA1 = xb + (size_t)atok[base + r1] * D_MODEL + swz_src_q(c1) * 8;
    const bf16* Bt = W1T + ((size_t)e * F_FF + nbase) * D_MODEL;
    const bf16* gB0 = Bt + (size_t)(c0 >> 2) * D_MODEL + swz_src_q(c0) * 8;
    const bf16* gB1 = Bt + (size_t)(c1 >> 2) * D_MODEL + swz_src_q(c1) * 8;
    f32x4 acc[4][4] = {};
    gemm128_core(gA0, gA1, gB0, gB1, D_MODEL, smem, acc);
    const int lane = tid & 63;
    const int w = tid >> 6;
    const int wm = w & 1, wn = w >> 1;
    const int lc = lane & 15, qd = lane >> 4;
    const bool oddE = (e & 1) != 0;
    #pragma unroll
    for (int i = 0; i < 4; ++i) {
        #pragma unroll
        for (int j = 0; j < 4; ++j) {
            int col = nbase + wn * 64 + j * 16 + lc;
            float bias = b1[e * F_FF + col];
            #pragma unroll
            for (int r = 0; r < 4; ++r) {
                int rloc = mloc + wm * 64 + i * 16 + qd * 4 + r;
                if (rloc < rows) {
                    float vv = acc[i][j][r] + bias;
                    vv = oddE ? silu_f(vv) : gelu_f(vv);
                    act[(size_t)(base + rloc) * F_FF + col] = (bf16)vv;
                }
            }
        }
    }
}

__global__ __launch_bounds__(256, 3) void expert_gemm2(
    const bf16* __restrict__ act, const bf16* __restrict__ W2T,
    const float* __restrict__ b2, const int* __restrict__ meta,
    float* __restrict__ eo) {
    __shared__ bf16 smem[24576];
    const int id = blockIdx.x;
    const int xcd = id & 7, slot = id >> 3;
    const int xt = slot % NX2;
    const int g = (slot / NX2) * 8 + xcd;
    const int e = g % N_EXP, y = g / N_EXP;
    int rows = meta[e];
    int mloc = y * 128;
    if (mloc >= rows) return;
    int base = meta[8 + e];
    int tid = threadIdx.x;
    int nbase = xt * 128;
    int c0 = tid, c1 = tid + 256;
    int r0 = mloc + (c0 >> 2); if (r0 > rows - 1) r0 = rows - 1;
    int r1 = mloc + (c1 >> 2); if (r1 > rows - 1) r1 = rows - 1;
    const bf16* gA0 = act + (size_t)(base + r0) * F_FF + swz_src_q(c0) * 8;
    const bf16* gA1 = act + (size_t)(base + r1) * F_FF + swz_src_q(c1) * 8;
    const bf16* Bt = W2T + ((size_t)e * D_MODEL + nbase) * F_FF;
    const bf16* gB0 = Bt + (size_t)(c0 >> 2) * F_FF + swz_src_q(c0) * 8;
    const bf16* gB1 = Bt + (size_t)(c1 >> 2) * F_FF + swz_src_q(c1) * 8;
    f32x4 acc[4][4] = {};
    gemm128_core(gA0, gA1, gB0, gB1, F_FF, smem, acc);
    const int lane = tid & 63;
    const int w = tid >> 6;
    const int wm = w & 1, wn = w >> 1;
    const int lc = lane & 15, qd = lane >> 4;
    #pragma unroll
    for (int i = 0; i < 4; ++i) {
        #pragma unroll
        for (int j = 0; j < 4; ++j) {
            int col = nbase + wn * 64 + j * 16 + lc;
            float bias = b2[e * D_MODEL + col];
            #pragma unroll
            for (int r = 0; r < 4; ++r) {
                int rloc = mloc + wm * 64 + i * 16 + qd * 4 + r;
                if (rloc < rows)
                    eo[(size_t)(base + rloc) * D_MODEL + col] = acc[i][j][r] + bias;
            }
        }
    }
}

// ---------------- weighted combine ------------------------------------------

__global__ __launch_bounds__(256) void combine_kernel(
    const float* __restrict__ eo, const int* __restrict__ ainv,
    const float* __restrict__ top_p, float* __restrict__ out) {
    int t = blockIdx.x;
    int s0 = ainv[2 * t], s1 = ainv[2 * t + 1];
    float p0 = top_p[2 * t], p1 = top_p[2 * t + 1];
    int c = threadIdx.x * 4;
    f32x4 a = *(const f32x4*)(eo + (size_t)s0 * D_MODEL + c);
    f32x4 b = *(const f32x4*)(eo + (size_t)s1 * D_MODEL + c);
    f32x4 o;
    #pragma unroll
    for (int k = 0; k < 4; ++k) o[k] = a[k] * p0 + b[k] * p1;
    *(f32x4*)(out + (size_t)t * D_MODEL + c) = o;
}

// ---------------- launch ----------------------------------------------------

extern "C" void kernel_launch(void* const* d_in, const int* in_sizes, int n_in,
                              void* d_out, int out_size, void* d_ws, size_t ws_size,
                              hipStream_t stream) {
    const float* x     = (const float*)d_in[0];
    const float* r1w   = (const float*)d_in[1];
    const float* r1b   = (const float*)d_in[2];
    const float* lng   = (const float*)d_in[3];
    const float* lnb   = (const float*)d_in[4];
    const float* r2w   = (const float*)d_in[5];
    const float* r2b   = (const float*)d_in[6];
    const float* temp  = (const float*)d_in[7];
    const float* rbias = (const float*)d_in[8];
    const float* W1    = (const float*)d_in[9];
    const float* b1    = (const float*)d_in[10];
    const float* W2    = (const float*)d_in[11];
    const float* b2    = (const float*)d_in[12];
    float* out = (float*)d_out;

    char* ws = (char*)d_ws;
    size_t off = 0;
    auto alloc = [&](size_t bytes) -> void* {
        void* p = ws + off;
        off = (off + bytes + 255) & ~(size_t)255;
        return p;
    };
    bf16*  xh    = (bf16*)alloc((size_t)N_TOK * D_MODEL * 2);
    bf16*  xl    = (bf16*)alloc((size_t)N_TOK * D_MODEL * 2);
    bf16*  r1wTh = (bf16*)alloc((size_t)H_R * D_MODEL * 2);
    bf16*  r1wTl = (bf16*)alloc((size_t)H_R * D_MODEL * 2);
    bf16*  W1T   = (bf16*)alloc((size_t)N_EXP * F_FF * D_MODEL * 2);
    bf16*  W2T   = (bf16*)alloc((size_t)N_EXP * D_MODEL * F_FF * 2);
    float* hp    = (float*)alloc((size_t)N_TOK * H_R * 4);
    int*   top_i = (int*)alloc((size_t)N_TOK * 2 * 4);
    float* top_p = (float*)alloc((size_t)N_TOK * 2 * 4);
    int*   meta  = (int*)alloc(256);
    int*   flags = (int*)alloc(FLAG_CAP * 4);
    int*   atok  = (int*)alloc((size_t)2 * N_TOK * 4);
    int*   ainv  = (int*)alloc((size_t)2 * N_TOK * 4);
    bf16*  actb  = (bf16*)alloc((size_t)2 * N_TOK * F_FF * 2);
    float* eo    = (float*)alloc((size_t)2 * N_TOK * D_MODEL * 4);
    (void)ws_size; (void)n_in; (void)in_sizes;

    hipMemsetAsync(meta, 0, 256, stream);

    convert_x_split<<<(N_TOK * D_MODEL) / (256 * 8), 256, 0, stream>>>(x, xh, xl);
    transpose_split<<<dim3(H_R / 32, D_MODEL / 32, 1), 256, 0, stream>>>(
        r1w, r1wTh, r1wTl, D_MODEL, H_R);

    router_gemm_fused<<<dim3(H_R / 128, N_TOK / 128, 1), 256, 0, stream>>>(
        xh, xl, r1wTh, r1wTl, hp);
    ln_router2<<<N_TOK / 4, 256, 0, stream>>>(
        hp, r1b, lng, lnb, r2w, r2b, temp, rbias, top_i, top_p, flags, meta);
    router_rescue<<<FLAG_CAP, 256, 0, stream>>>(
        x, r1w, r1b, lng, lnb, r2w, r2b, temp, rbias, flags, meta, top_i, top_p);
    route_pack<<<1, RP_T, 0, stream>>>(top_i, meta, atok, ainv);

    // weight transposes placed just before their consumers (L2/L3-warm)
    transpose_bf16_64<<<dim3(F_FF / 64, D_MODEL / 64, N_EXP), 256, 0, stream>>>(
        W1, W1T, D_MODEL, F_FF);
    transpose_bf16_64<<<dim3(D_MODEL / 64, F_FF / 64, N_EXP), 256, 0, stream>>>(
        W2, W2T, F_FF, D_MODEL);

    expert_gemm1<<<(N_TOK / 128) * N_EXP * NX1, 256, 0, stream>>>(
        xh, W1T, b1, meta, atok, actb);
    expert_gemm2<<<(N_TOK / 128) * N_EXP * NX2, 256, 0, stream>>>(
        actb, W2T, b2, meta, eo);
    combine_kernel<<<N_TOK, 256, 0, stream>>>(eo, ainv, top_p, out);
}